// Round 15
// baseline (143.664 us; speedup 1.0000x reference)
//
#include <hip/hip_runtime.h>
#include <hip/hip_bf16.h>
#include <stdint.h>

#define S_LEN 2048
#define BATCH 2
#define EMB   1024
#define NH    16
#define HD    64
#define LOG2E 1.4426950408889634f

typedef __bf16 bf16x8 __attribute__((ext_vector_type(8)));
typedef float  f32x4  __attribute__((ext_vector_type(4)));
typedef unsigned short ushort8 __attribute__((ext_vector_type(8)));

__device__ __forceinline__ unsigned short f2bf(float f) {
  __bf16 h = (__bf16)f;
  return __builtin_bit_cast(unsigned short, h);
}

__device__ __forceinline__ ushort8 cvt8(const float4 a, const float4 b) {
  ushort8 o;
  o[0]=f2bf(a.x); o[1]=f2bf(a.y); o[2]=f2bf(a.z); o[3]=f2bf(a.w);
  o[4]=f2bf(b.x); o[5]=f2bf(b.y); o[6]=f2bf(b.z); o[7]=f2bf(b.w);
  return o;
}

__device__ __forceinline__ uint2 pack4(const f32x4 v) {
  uint2 r;
  r.x = (unsigned)f2bf(v[0]) | ((unsigned)f2bf(v[1]) << 16);
  r.y = (unsigned)f2bf(v[2]) | ((unsigned)f2bf(v[3]) << 16);
  return r;
}

#define GLOAD16(g, l) __builtin_amdgcn_global_load_lds( \
    (const __attribute__((address_space(1))) void*)(g),  \
    (__attribute__((address_space(3))) void*)(l), 16, 0, 0)

// ---------------- fp32 -> bf16 conversion (single src) ----------------
__global__ __launch_bounds__(256) void k_cvt(const float* __restrict__ src,
                                             unsigned short* __restrict__ dst,
                                             int n) {
  int i = (blockIdx.x*256 + threadIdx.x)*8;
  if (i >= n) return;
  const float4* s4 = (const float4*)(src + i);
  *(ushort8*)(dst + i) = cvt8(s4[0], s4[1]);
}

// ------- fused cvt: x (2048 blk) + wq/wk/wv (512 each) [+ wo (512)] ------
__global__ __launch_bounds__(256) void k_cvt_all(
    const float* __restrict__ x,
    const float* __restrict__ wq, const float* __restrict__ wk,
    const float* __restrict__ wv, const float* __restrict__ wo,
    unsigned short* __restrict__ xb, unsigned short* __restrict__ wb,
    unsigned short* __restrict__ wob) {
  const int b = blockIdx.x;
  const float* src;
  unsigned short* dst;
  int off;
  if (b < 2048) { src = x; dst = xb; off = b; }
  else {
    const int t = b - 2048;
    const int z = t >> 9;
    if (z < 3) { src = (z==0) ? wq : ((z==1) ? wk : wv); dst = wb + (size_t)z*EMB*EMB; }
    else       { src = wo; dst = wob; }
    off = t & 511;
  }
  const int i = (off*256 + threadIdx.x)*8;
  const float4* s4 = (const float4*)(src + i);
  *(ushort8*)(dst + i) = cvt8(s4[0], s4[1]);
}

// ---------------- QKV projection, A+B bf16, double-buffered, swizzled -----
// LDS: rows paired into 128B lines; slot(row,q) = ((row&1)*4+q) ^ (line&7)
// -> frag reads are 2-way (free). Source pre-swizzled, dest linear (rule 21).
__global__ __launch_bounds__(256) void k_qkv_bb(
    const unsigned short* __restrict__ xb,
    const unsigned short* __restrict__ wb,
    const float* __restrict__ bq, const float* __restrict__ bk,
    const float* __restrict__ bv,
    unsigned short* __restrict__ Qb, unsigned short* __restrict__ Kb,
    unsigned short* __restrict__ Vtb)
{
  __shared__ unsigned short Al[2][128*32];
  __shared__ unsigned short Bl[2][128*32];
  const int tid = threadIdx.x;
  const int lin  = blockIdx.x;
  const int wgid = (lin & 7)*96 + (lin >> 3);
  const int mb   = wgid / 24;
  const int t    = wgid % 24;
  const int z    = t >> 3;
  const int nb   = t & 7;
  const int m0 = mb * 128;
  const int n0 = nb * 128;
  const int w = tid >> 6, lane = tid & 63;
  const int wr = w >> 1, wc = w & 1;
  const int lr = lane & 15, lhi = lane >> 4;
  const unsigned short* wz = wb + (size_t)z * (EMB*EMB);

  // staging: thread c fills physical 16B slot c; source = inverse swizzle
  const unsigned short* ag[2];
  const unsigned short* bg[2];
  int ub[2];
#pragma unroll
  for (int j=0;j<2;++j) {
    const int c    = j*256 + tid;
    const int line = c >> 3;
    const int sp   = (c & 7) ^ (line & 7);
    const int row  = line*2 + (sp >> 2);
    const int q    = sp & 3;
    ag[j] = xb + (size_t)(m0+row)*EMB + q*8;
    bg[j] = wz + (size_t)(n0+row)*EMB + q*8;
    ub[j] = (j*256 + (tid & 192)) * 16;
  }

  auto STAGE = [&](int k0, int b2) {
#pragma unroll
    for (int j=0;j<2;++j) {
      GLOAD16(ag[j] + k0, (char*)Al[b2] + ub[j]);
      GLOAD16(bg[j] + k0, (char*)Bl[b2] + ub[j]);
    }
  };

  // frag-read bases (t-invariant): slot = ((lr&1)*4+lhi) ^ (lr>>1)
  const int asl  = (((lr & 1) << 2) + lhi) ^ (lr >> 1);
  const int rb   = (lr >> 1)*128 + asl*16;
  const int abase = wr*4096 + rb;
  const int bbase = wc*4096 + rb;

  f32x4 acc[4][4];
#pragma unroll
  for (int m=0;m<4;++m)
#pragma unroll
    for (int n=0;n<4;++n) acc[m][n] = (f32x4){0.f,0.f,0.f,0.f};

  STAGE(0, 0);
  int bbuf = 0;
  for (int k0 = 0; k0 < EMB; k0 += 32) {
    if (k0 + 32 < EMB) {
      STAGE(k0 + 32, bbuf^1);
      asm volatile("s_waitcnt vmcnt(4)" ::: "memory");
    } else {
      asm volatile("s_waitcnt vmcnt(0)" ::: "memory");
    }
    __builtin_amdgcn_s_barrier();

    bf16x8 af[4], bfr[4];
#pragma unroll
    for (int m=0;m<4;++m) af[m]  = *(const bf16x8*)((char*)Al[bbuf] + abase + m*1024);
#pragma unroll
    for (int n=0;n<4;++n) bfr[n] = *(const bf16x8*)((char*)Bl[bbuf] + bbase + n*1024);
    __builtin_amdgcn_s_setprio(1);
#pragma unroll
    for (int m=0;m<4;++m)
#pragma unroll
      for (int n=0;n<4;++n)
        acc[m][n] = __builtin_amdgcn_mfma_f32_16x16x32_bf16(af[m], bfr[n], acc[m][n], 0,0,0);
    __builtin_amdgcn_s_setprio(0);

    __builtin_amdgcn_s_barrier();
    bbuf ^= 1;
  }

  const float scale = (z==0) ? 0.125f*LOG2E : 1.0f;
  const float* bias = (z==0) ? bq : ((z==1) ? bk : bv);
#pragma unroll
  for (int m=0;m<4;++m)
#pragma unroll
    for (int n=0;n<4;++n)
#pragma unroll
      for (int r=0;r<4;++r) {
        const int rr   = m0 + wr*64 + m*16 + lhi*4 + r;
        const int fcol = n0 + wc*64 + n*16 + lr;
        const float v = (acc[m][n][r] + bias[fcol]) * scale;
        const unsigned short ov = f2bf(v);
        const int i = rr >> 1, bsel = rr & 1;
        const int h = fcol >> 6, d = fcol & 63;
        const int hh = bsel*NH + h;
        if (z == 0)      Qb [((size_t)hh*S_LEN + i)*HD + d] = ov;
        else if (z == 1) Kb [((size_t)hh*S_LEN + i)*HD + d] = ov;
        else             Vtb[((size_t)hh*HD + d)*S_LEN + i] = ov;
      }
}

// ---------------- QKV projection, bf16 A / fp32 B (32MB tier) ------------
__global__ __launch_bounds__(256) void k_qkv_bf(
    const unsigned short* __restrict__ xb,
    const float* __restrict__ wq, const float* __restrict__ wk,
    const float* __restrict__ wv,
    const float* __restrict__ bq, const float* __restrict__ bk,
    const float* __restrict__ bv,
    unsigned short* __restrict__ Qb, unsigned short* __restrict__ Kb,
    unsigned short* __restrict__ Vtb)
{
  __shared__ unsigned short Al[128*32];
  __shared__ unsigned short Bl[128*32];
  const int tid = threadIdx.x;
  const int lin  = blockIdx.x;
  const int wgid = (lin & 7)*96 + (lin >> 3);
  const int mb   = wgid / 24;
  const int t    = wgid % 24;
  const int z    = t >> 3;
  const int nb   = t & 7;
  const int m0 = mb * 128;
  const int n0 = nb * 128;
  const int w = tid >> 6, lane = tid & 63;
  const int wr = w >> 1, wc = w & 1;
  const int lr = lane & 15, lhi = lane >> 4;
  const float* wz = (z==0) ? wq : ((z==1) ? wk : wv);

  f32x4 acc[4][4];
#pragma unroll
  for (int m=0;m<4;++m)
#pragma unroll
    for (int n=0;n<4;++n) acc[m][n] = (f32x4){0.f,0.f,0.f,0.f};

  for (int k0 = 0; k0 < EMB; k0 += 32) {
    float4 b0[2], b1[2];
#pragma unroll
    for (int j = 0; j < 2; ++j) {
      const int c   = j*256 + tid;
      const int row = c >> 2;
      const int col = (c & 3) << 3;
      const float* bp = wz + (size_t)(n0+row)*EMB + k0 + col;
      b0[j] = *(const float4*)bp;  b1[j] = *(const float4*)(bp+4);
    }
    __syncthreads();
#pragma unroll
    for (int j = 0; j < 2; ++j) {
      const int c   = j*256 + tid;
      const int row = c >> 2;
      const int col = (c & 3) << 3;
      const int ub  = (j*256 + (tid & 192)) * 16;
      GLOAD16(xb + (size_t)(m0+row)*EMB + k0 + col, (char*)Al + ub);
      *(ushort8*)&Bl[row*32 + col] = cvt8(b0[j], b1[j]);
    }
    __syncthreads();
    bf16x8 af[4], bfr[4];
#pragma unroll
    for (int m=0;m<4;++m) af[m]  = *(const bf16x8*)&Al[(wr*64 + m*16 + lr)*32 + lhi*8];
#pragma unroll
    for (int n=0;n<4;++n) bfr[n] = *(const bf16x8*)&Bl[(wc*64 + n*16 + lr)*32 + lhi*8];
#pragma unroll
    for (int m=0;m<4;++m)
#pragma unroll
      for (int n=0;n<4;++n)
        acc[m][n] = __builtin_amdgcn_mfma_f32_16x16x32_bf16(af[m], bfr[n], acc[m][n], 0,0,0);
  }

  const float scale = (z==0) ? 0.125f*LOG2E : 1.0f;
  const float* bias = (z==0) ? bq : ((z==1) ? bk : bv);
#pragma unroll
  for (int m=0;m<4;++m)
#pragma unroll
    for (int n=0;n<4;++n)
#pragma unroll
      for (int r=0;r<4;++r) {
        const int rr   = m0 + wr*64 + m*16 + lhi*4 + r;
        const int fcol = n0 + wc*64 + n*16 + lr;
        const float v = (acc[m][n][r] + bias[fcol]) * scale;
        const unsigned short ov = f2bf(v);
        const int i = rr >> 1, bsel = rr & 1;
        const int h = fcol >> 6, d = fcol & 63;
        const int hh = bsel*NH + h;
        if (z == 0)      Qb [((size_t)hh*S_LEN + i)*HD + d] = ov;
        else if (z == 1) Kb [((size_t)hh*S_LEN + i)*HD + d] = ov;
        else             Vtb[((size_t)hh*HD + d)*S_LEN + i] = ov;
      }
}

// ---------------- QKV projection, fp32 A (small-ws fallback) ------------
__global__ __launch_bounds__(256) void k_qkv(
    const float* __restrict__ xA, int a_rs, int ishift,
    const float* __restrict__ wq, const float* __restrict__ wk,
    const float* __restrict__ wv,
    const float* __restrict__ bq, const float* __restrict__ bk,
    const float* __restrict__ bv,
    unsigned short* __restrict__ Qb, unsigned short* __restrict__ Kb,
    unsigned short* __restrict__ Vtb)
{
  __shared__ unsigned short Al[128*32];
  __shared__ unsigned short Bl[128*32];
  const int tid = threadIdx.x;
  const int z  = blockIdx.z;
  const int m0 = blockIdx.x * 128;
  const int n0 = blockIdx.y * 128;
  const int w = tid >> 6, lane = tid & 63;
  const int wr = w >> 1, wc = w & 1;
  const int lr = lane & 15, lhi = lane >> 4;
  const float* wz = (z==0) ? wq : ((z==1) ? wk : wv);

  f32x4 acc[4][4];
#pragma unroll
  for (int m=0;m<4;++m)
#pragma unroll
    for (int n=0;n<4;++n) acc[m][n] = (f32x4){0.f,0.f,0.f,0.f};

  for (int k0 = 0; k0 < EMB; k0 += 32) {
    float4 a0[2], a1[2], b0[2], b1[2];
#pragma unroll
    for (int j = 0; j < 2; ++j) {
      const int c   = j*256 + tid;
      const int row = c >> 2;
      const int col = (c & 3) << 3;
      const float* ap = xA + (size_t)(m0+row)*a_rs + k0 + col;
      const float* bp = wz + (size_t)(n0+row)*EMB + k0 + col;
      a0[j] = *(const float4*)ap;  a1[j] = *(const float4*)(ap+4);
      b0[j] = *(const float4*)bp;  b1[j] = *(const float4*)(bp+4);
    }
    __syncthreads();
#pragma unroll
    for (int j = 0; j < 2; ++j) {
      const int c   = j*256 + tid;
      const int row = c >> 2;
      const int col = (c & 3) << 3;
      *(ushort8*)&Al[row*32 + col] = cvt8(a0[j], a1[j]);
      *(ushort8*)&Bl[row*32 + col] = cvt8(b0[j], b1[j]);
    }
    __syncthreads();
    bf16x8 af[4], bfr[4];
#pragma unroll
    for (int m=0;m<4;++m) af[m]  = *(const bf16x8*)&Al[(wr*64 + m*16 + lr)*32 + lhi*8];
#pragma unroll
    for (int n=0;n<4;++n) bfr[n] = *(const bf16x8*)&Bl[(wc*64 + n*16 + lr)*32 + lhi*8];
#pragma unroll
    for (int m=0;m<4;++m)
#pragma unroll
      for (int n=0;n<4;++n)
        acc[m][n] = __builtin_amdgcn_mfma_f32_16x16x32_bf16(af[m], bfr[n], acc[m][n], 0,0,0);
  }

  const float scale = (z==0) ? 0.125f*LOG2E : 1.0f;
  const float* bias = (z==0) ? bq : ((z==1) ? bk : bv);
  const int bmask = (1 << ishift) - 1;
#pragma unroll
  for (int m=0;m<4;++m)
#pragma unroll
    for (int n=0;n<4;++n)
#pragma unroll
      for (int r=0;r<4;++r) {
        const int rr   = m0 + wr*64 + m*16 + lhi*4 + r;
        const int fcol = n0 + wc*64 + n*16 + lr;
        const float v = (acc[m][n][r] + bias[fcol]) * scale;
        const unsigned short ov = f2bf(v);
        const int i = rr >> ishift, bsel = rr & bmask;
        const int h = fcol >> 6, d = fcol & 63;
        const int hh = bsel*NH + h;
        if (z == 0)      Qb [((size_t)hh*S_LEN + i)*HD + d] = ov;
        else if (z == 1) Kb [((size_t)hh*S_LEN + i)*HD + d] = ov;
        else             Vtb[((size_t)hh*HD + d)*S_LEN + i] = ov;
      }
}

// ---------------- causal flash attention (V from global regs) -------------
// K double-buffered in LDS (swizzled); V frags loaded straight from the
// L2-resident Vt into registers at compute start (latency hides under QK),
// deleting the VL buffer and 8 of 18 LDS reads per wave-tile.
__global__ __launch_bounds__(256,4) void k_attn_u(
    const unsigned short* __restrict__ Q,
    const unsigned short* __restrict__ K,
    const unsigned short* __restrict__ Vt,
    unsigned short* __restrict__ ctx, int bshift, int hsh)
{
  __shared__ unsigned short KL[2][64*64];
  __shared__ unsigned short Pl[4][16*64];

  const int tid = threadIdx.x;
  const int w = tid >> 6, lane = tid & 63;
  const int lr = lane & 15, lhi = lane >> 4;

  const int lin = blockIdx.x;
  const int cc  = lin >> hsh;
  const int chunk = (cc < 16) ? cc : (47 - cc);
  const int hh  = lin & ((1 << hsh) - 1);
  const int q0  = chunk*64 + w*16;

  const unsigned short* Qh = Q  + (size_t)hh*S_LEN*HD;
  const unsigned short* Kh = K  + (size_t)hh*S_LEN*HD;
  const unsigned short* Vh = Vt + (size_t)hh*HD*S_LEN;
  char* Pw = (char*)Pl[w];

  const int xm = (lr & 7) << 4;
  int kvb[2];
#pragma unroll
  for (int kf=0;kf<2;++kf) kvb[kf] = lr*128 + ((kf*64 + lhi*16) ^ xm);
  int pwb[4];
#pragma unroll
  for (int kn=0;kn<4;++kn)
    pwb[kn] = lr*128 + ((kn*32 + lhi*8) ^ xm);

  const unsigned short* kga[2];
#pragma unroll
  for (int j=0;j<2;++j) {
    const int c   = j*256 + tid;
    const int row = c >> 3;
    const int sb  = (c*16) ^ ((row & 7) << 4);
    const int el  = (sb & 127) >> 1;
    kga[j] = Kh + (size_t)row*HD + el;
  }
  const int ub0 = (tid & 192) * 16;
  const unsigned short* vgb = Vh + (size_t)lr*S_LEN + lhi*8;  // + dn*32768 + ks*32 + t*64

  bf16x8 qf[2];
#pragma unroll
  for (int kf=0;kf<2;++kf)
    qf[kf] = *(const bf16x8*)&Qh[(size_t)(q0 + lr)*HD + kf*32 + lhi*8];

  f32x4 o[4];
  float rl = 0.f;
#pragma unroll
  for (int dn=0;dn<4;++dn) o[dn] = (f32x4){0.f,0.f,0.f,0.f};

  const int tmax = chunk + 1;

  auto STAGE = [&](int tt, int bb2) {
#pragma unroll
    for (int j=0;j<2;++j)
      GLOAD16(kga[j] + (size_t)tt*4096, (char*)KL[bb2] + ub0 + j*4096);
  };

  STAGE(0, 0);
  int bb = 0;
  for (int t = 0; t < tmax; ++t) {
    if (t + 1 < tmax) {
      STAGE(t+1, bb^1);
      asm volatile("s_waitcnt vmcnt(2)" ::: "memory");
    } else {
      asm volatile("s_waitcnt vmcnt(0)" ::: "memory");
    }
    __builtin_amdgcn_s_barrier();

    const int kv0 = t*64;
    const char* KB = (const char*)KL[bb];

    // V frags for this tile: straight from L2-resident global into regs;
    // issued first so latency hides under QK^T + softmax
    bf16x8 vf[2][4];
#pragma unroll
    for (int ks=0;ks<2;++ks)
#pragma unroll
      for (int dn=0;dn<4;++dn)
        vf[ks][dn] = *(const bf16x8*)(vgb + dn*32768 + ks*32 + kv0);

    f32x4 st[4];
#pragma unroll
    for (int kn=0;kn<4;++kn) st[kn] = (f32x4){0.f,0.f,0.f,0.f};

    __builtin_amdgcn_s_setprio(1);
#pragma unroll
    for (int kn=0;kn<4;++kn)
#pragma unroll
      for (int kf=0;kf<2;++kf) {
        const bf16x8 kfr = *(const bf16x8*)(KB + kvb[kf] + kn*2048);
        st[kn] = __builtin_amdgcn_mfma_f32_16x16x32_bf16(kfr, qf[kf], st[kn], 0,0,0);
      }
    __builtin_amdgcn_s_setprio(0);

    if (t == tmax-1) {   // diagonal tile: mask k > q (exp2f(-1e30) == 0)
      const int q = q0 + lr;
#pragma unroll
      for (int kn=0;kn<4;++kn)
#pragma unroll
        for (int r=0;r<4;++r) {
          const int k = kv0 + kn*16 + lhi*4 + r;
          if (k > q) st[kn][r] = -1.0e30f;
        }
    }

    // no-max softmax
#pragma unroll
    for (int kn=0;kn<4;++kn)
#pragma unroll
      for (int r=0;r<4;++r) {
        const float p = exp2f(st[kn][r]);
        st[kn][r] = p;
        rl += p;
      }

#pragma unroll
    for (int kn=0;kn<4;++kn)
      *(uint2*)(Pw + pwb[kn]) = pack4(st[kn]);

    // PV: O^T += MFMA(A = V^T frags (regs), B = P rows (LDS))
#pragma unroll
    for (int ks=0;ks<2;++ks) {
      const bf16x8 pfr = *(const bf16x8*)(Pw + kvb[ks]);
      __builtin_amdgcn_s_setprio(1);
#pragma unroll
      for (int dn=0;dn<4;++dn)
        o[dn] = __builtin_amdgcn_mfma_f32_16x16x32_bf16(vf[ks][dn], pfr, o[dn], 0,0,0);
      __builtin_amdgcn_s_setprio(0);
    }

    __builtin_amdgcn_s_barrier();
    bb ^= 1;
  }

  rl += __shfl_xor(rl, 16);
  rl += __shfl_xor(rl, 32);
  const int h = hh & (NH-1);
  const int badd = hh >> 4;
  const float inv = 1.0f / rl;
  const int q = q0 + lr;
  const size_t trow = ((size_t)q << bshift) + badd;
#pragma unroll
  for (int dn=0;dn<4;++dn) {
    f32x4 ov;
#pragma unroll
    for (int r=0;r<4;++r) ov[r] = o[dn][r]*inv;
    *(uint2*)&ctx[trow*EMB + h*HD + dn*16 + lhi*4] = pack4(ov);
  }
}

// ---------------- output projection, bf16 A+B, dbuf, swizzled -------------
__global__ __launch_bounds__(256) void k_oproj_bf(
    const unsigned short* __restrict__ ctxA,
    const unsigned short* __restrict__ wob,
    const float* __restrict__ bo,
    float* __restrict__ out)
{
  __shared__ unsigned short Al[2][128*32];
  __shared__ unsigned short Bl[2][128*32];
  const int tid = threadIdx.x;
  const int m0 = blockIdx.x * 128;
  const int n0 = blockIdx.y * 128;
  const int w = tid >> 6, lane = tid & 63;
  const int wr = w >> 1, wc = w & 1;
  const int lr = lane & 15, lhi = lane >> 4;

  const unsigned short* ag[2];
  const unsigned short* bg[2];
  int ub[2];
#pragma unroll
  for (int j=0;j<2;++j) {
    const int c    = j*256 + tid;
    const int line = c >> 3;
    const int sp   = (c & 7) ^ (line & 7);
    const int row  = line*2 + (sp >> 2);
    const int q    = sp & 3;
    ag[j] = ctxA + (size_t)(m0+row)*EMB + q*8;
    bg[j] = wob  + (size_t)(n0+row)*EMB + q*8;
    ub[j] = (j*256 + (tid & 192)) * 16;
  }

  auto STAGE = [&](int k0, int b2) {
#pragma unroll
    for (int j=0;j<2;++j) {
      GLOAD16(ag[j] + k0, (char*)Al[b2] + ub[j]);
      GLOAD16(bg[j] + k0, (char*)Bl[b2] + ub[j]);
    }
  };

  const int asl  = (((lr & 1) << 2) + lhi) ^ (lr >> 1);
  const int rb   = (lr >> 1)*128 + asl*16;
  const int abase = wr*4096 + rb;
  const int bbase = wc*4096 + rb;

  f32x4 acc[4][4];
#pragma unroll
  for (int m=0;m<4;++m)
#pragma unroll
    for (int n=0;n<4;++n) acc[m][n] = (f32x4){0.f,0.f,0.f,0.f};

  STAGE(0, 0);
  int bbuf = 0;
  for (int k0 = 0; k0 < EMB; k0 += 32) {
    if (k0 + 32 < EMB) {
      STAGE(k0 + 32, bbuf^1);
      asm volatile("s_waitcnt vmcnt(4)" ::: "memory");
    } else {
      asm volatile("s_waitcnt vmcnt(0)" ::: "memory");
    }
    __builtin_amdgcn_s_barrier();

    bf16x8 af[4], bfr[4];
#pragma unroll
    for (int m=0;m<4;++m) af[m]  = *(const bf16x8*)((char*)Al[bbuf] + abase + m*1024);
#pragma unroll
    for (int n=0;n<4;++n) bfr[n] = *(const bf16x8*)((char*)Bl[bbuf] + bbase + n*1024);
    __builtin_amdgcn_s_setprio(1);
#pragma unroll
    for (int m=0;m<4;++m)
#pragma unroll
      for (int n=0;n<4;++n)
        acc[m][n] = __builtin_amdgcn_mfma_f32_16x16x32_bf16(af[m], bfr[n], acc[m][n], 0,0,0);
    __builtin_amdgcn_s_setprio(0);

    __builtin_amdgcn_s_barrier();
    bbuf ^= 1;
  }

#pragma unroll
  for (int m=0;m<4;++m)
#pragma unroll
    for (int n=0;n<4;++n)
#pragma unroll
      for (int r=0;r<4;++r) {
        const int rr   = m0 + wr*64 + m*16 + lhi*4 + r;
        const int fcol = n0 + wc*64 + n*16 + lr;
        out[(size_t)rr*EMB + fcol] = acc[m][n][r] + bo[fcol];
      }
}

// ---------------- output projection, fp32 B (fallback) -------------------
__global__ __launch_bounds__(256) void k_oproj(
    const unsigned short* __restrict__ ctxA,
    const float* __restrict__ wo,
    const float* __restrict__ bo,
    float* __restrict__ outb, int orm)
{
  __shared__ unsigned short Al[128*32];
  __shared__ unsigned short Bl[128*32];
  const int tid = threadIdx.x;
  const int m0 = blockIdx.x * 128;
  const int n0 = blockIdx.y * 128;
  const int w = tid >> 6, lane = tid & 63;
  const int wr = w >> 1, wc = w & 1;
  const int lr = lane & 15, lhi = lane >> 4;

  f32x4 acc[4][4];
#pragma unroll
  for (int m=0;m<4;++m)
#pragma unroll
    for (int n=0;n<4;++n) acc[m][n] = (f32x4){0.f,0.f,0.f,0.f};

  for (int k0 = 0; k0 < EMB; k0 += 32) {
    float4 b0[2], b1[2];
#pragma unroll
    for (int j = 0; j < 2; ++j) {
      const int c   = j*256 + tid;
      const int row = c >> 2;
      const int col = (c & 3) << 3;
      const float* bp = wo + (size_t)(n0+row)*EMB + k0 + col;
      b0[j] = *(const float4*)bp;  b1[j] = *(const float4*)(bp+4);
    }
    __syncthreads();
#pragma unroll
    for (int j = 0; j < 2; ++j) {
      const int c   = j*256 + tid;
      const int row = c >> 2;
      const int col = (c & 3) << 3;
      const int ub  = (j*256 + (tid & 192)) * 16;
      GLOAD16(ctxA + (size_t)(m0+row)*EMB + k0 + col, (char*)Al + ub);
      *(ushort8*)&Bl[row*32 + col] = cvt8(b0[j], b1[j]);
    }
    __syncthreads();
    bf16x8 af[4], bfr[4];
#pragma unroll
    for (int m=0;m<4;++m) af[m]  = *(const bf16x8*)&Al[(wr*64 + m*16 + lr)*32 + lhi*8];
#pragma unroll
    for (int n=0;n<4;++n) bfr[n] = *(const bf16x8*)&Bl[(wc*64 + n*16 + lr)*32 + lhi*8];
#pragma unroll
    for (int m=0;m<4;++m)
#pragma unroll
      for (int n=0;n<4;++n)
        acc[m][n] = __builtin_amdgcn_mfma_f32_16x16x32_bf16(af[m], bfr[n], acc[m][n], 0,0,0);
  }

#pragma unroll
  for (int m=0;m<4;++m)
#pragma unroll
    for (int n=0;n<4;++n)
#pragma unroll
      for (int r=0;r<4;++r) {
        const int rr   = m0 + wr*64 + m*16 + lhi*4 + r;
        const int fcol = n0 + wc*64 + n*16 + lr;
        outb[(size_t)rr*orm*EMB + fcol] = acc[m][n][r] + bo[fcol];
      }
}

// ---------------- launch ----------------
extern "C" void kernel_launch(void* const* d_in, const int* in_sizes, int n_in,
                              void* d_out, int out_size, void* d_ws, size_t ws_size,
                              hipStream_t stream) {
  const float* x  = (const float*)d_in[0];
  const float* wq = (const float*)d_in[1];
  const float* bq = (const float*)d_in[2];
  const float* wk = (const float*)d_in[3];
  const float* bk = (const float*)d_in[4];
  const float* wv = (const float*)d_in[5];
  const float* bv = (const float*)d_in[6];
  const float* wo = (const float*)d_in[7];
  const float* bo = (const float*)d_in[8];
  float* out = (float*)d_out;

  char* ws = (char*)d_ws;
  const size_t MB = (size_t)1 << 20;

  if (ws_size >= 40*MB) {
    unsigned short* Q   = (unsigned short*)(ws + 0*MB);
    unsigned short* K   = (unsigned short*)(ws + 8*MB);
    unsigned short* Vt  = (unsigned short*)(ws + 16*MB);
    unsigned short* wb  = (unsigned short*)(ws + 24*MB);
    unsigned short* xb  = (unsigned short*)(ws + 30*MB);
    unsigned short* wob = (unsigned short*)(ws + 38*MB);
    unsigned short* cx  = (unsigned short*)(ws + 24*MB);

    k_cvt_all<<<4096, 256, 0, stream>>>(x, wq, wk, wv, wo, xb, wb, wob);
    k_qkv_bb<<<768, 256, 0, stream>>>(xb, wb, bq,bk,bv, Q, K, Vt);
    k_attn_u<<<1024, 256, 0, stream>>>(Q, K, Vt, cx, 1, 5);
    k_oproj_bf<<<dim3(32,8), 256, 0, stream>>>(cx, wob, bo, out);
  } else if (ws_size >= 38*MB) {
    unsigned short* Q   = (unsigned short*)(ws + 0*MB);
    unsigned short* K   = (unsigned short*)(ws + 8*MB);
    unsigned short* Vt  = (unsigned short*)(ws + 16*MB);
    unsigned short* wb  = (unsigned short*)(ws + 24*MB);
    unsigned short* xb  = (unsigned short*)(ws + 30*MB);
    unsigned short* cx  = (unsigned short*)(ws + 24*MB);
    unsigned short* wob = Vt;

    k_cvt_all<<<3584, 256, 0, stream>>>(x, wq, wk, wv, wo, xb, wb, (unsigned short*)0);
    k_qkv_bb<<<768, 256, 0, stream>>>(xb, wb, bq,bk,bv, Q, K, Vt);
    k_attn_u<<<1024, 256, 0, stream>>>(Q, K, Vt, cx, 1, 5);
    k_cvt<<<512, 256, 0, stream>>>(wo, wob, EMB*EMB);
    k_oproj_bf<<<dim3(32,8), 256, 0, stream>>>(cx, wob, bo, out);
  } else if (ws_size >= 32*MB) {
    unsigned short* Q   = (unsigned short*)(ws + 0*MB);
    unsigned short* K   = (unsigned short*)(ws + 8*MB);
    unsigned short* Vt  = (unsigned short*)(ws + 16*MB);
    unsigned short* cx  = (unsigned short*)(ws + 24*MB);
    unsigned short* xb  = cx;
    unsigned short* wob = Vt;

    k_cvt<<<2048, 256, 0, stream>>>(x, xb, (S_LEN*BATCH)*EMB);
    k_qkv_bf<<<768, 256, 0, stream>>>(xb, wq,wk,wv, bq,bk,bv, Q, K, Vt);
    k_attn_u<<<1024, 256, 0, stream>>>(Q, K, Vt, cx, 1, 5);
    k_cvt<<<512, 256, 0, stream>>>(wo, wob, EMB*EMB);
    k_oproj_bf<<<dim3(32,8), 256, 0, stream>>>(cx, wob, bo, out);
  } else {
    unsigned short* Q  = (unsigned short*)(ws + 0*MB);
    unsigned short* K  = (unsigned short*)(ws + 4*MB);
    unsigned short* Vt = (unsigned short*)(ws + 8*MB);
    unsigned short* cx = (unsigned short*)(ws + 12*MB);
    for (int b = 0; b < 2; ++b) {
      k_qkv<<<dim3(16,8,3), 256, 0, stream>>>(x + b*EMB, 2*EMB, 0,
                                              wq,wk,wv, bq,bk,bv, Q,K,Vt);
      k_attn_u<<<512, 256, 0, stream>>>(Q, K, Vt, cx, 0, 4);
      k_oproj<<<dim3(16,8), 256, 0, stream>>>(cx, wo, bo, out + b*EMB, 2);
    }
  }
}

// Round 16
// 111.750 us; speedup vs baseline: 1.2856x; 1.2856x over previous
//
#include <hip/hip_runtime.h>
#include <hip/hip_bf16.h>
#include <stdint.h>

#define S_LEN 2048
#define BATCH 2
#define EMB   1024
#define NH    16
#define HD    64
#define LOG2E 1.4426950408889634f

typedef __bf16 bf16x8 __attribute__((ext_vector_type(8)));
typedef float  f32x4  __attribute__((ext_vector_type(4)));
typedef unsigned short ushort8 __attribute__((ext_vector_type(8)));

__device__ __forceinline__ unsigned short f2bf(float f) {
  __bf16 h = (__bf16)f;
  return __builtin_bit_cast(unsigned short, h);
}

__device__ __forceinline__ ushort8 cvt8(const float4 a, const float4 b) {
  ushort8 o;
  o[0]=f2bf(a.x); o[1]=f2bf(a.y); o[2]=f2bf(a.z); o[3]=f2bf(a.w);
  o[4]=f2bf(b.x); o[5]=f2bf(b.y); o[6]=f2bf(b.z); o[7]=f2bf(b.w);
  return o;
}

__device__ __forceinline__ uint2 pack4(const f32x4 v) {
  uint2 r;
  r.x = (unsigned)f2bf(v[0]) | ((unsigned)f2bf(v[1]) << 16);
  r.y = (unsigned)f2bf(v[2]) | ((unsigned)f2bf(v[3]) << 16);
  return r;
}

#define GLOAD16(g, l) __builtin_amdgcn_global_load_lds( \
    (const __attribute__((address_space(1))) void*)(g),  \
    (__attribute__((address_space(3))) void*)(l), 16, 0, 0)

// ---------------- fp32 -> bf16 conversion (single src) ----------------
__global__ __launch_bounds__(256) void k_cvt(const float* __restrict__ src,
                                             unsigned short* __restrict__ dst,
                                             int n) {
  int i = (blockIdx.x*256 + threadIdx.x)*8;
  if (i >= n) return;
  const float4* s4 = (const float4*)(src + i);
  *(ushort8*)(dst + i) = cvt8(s4[0], s4[1]);
}

// ------- fused cvt: x (2048 blk) + wq/wk/wv (512 each) [+ wo (512)] ------
__global__ __launch_bounds__(256) void k_cvt_all(
    const float* __restrict__ x,
    const float* __restrict__ wq, const float* __restrict__ wk,
    const float* __restrict__ wv, const float* __restrict__ wo,
    unsigned short* __restrict__ xb, unsigned short* __restrict__ wb,
    unsigned short* __restrict__ wob) {
  const int b = blockIdx.x;
  const float* src;
  unsigned short* dst;
  int off;
  if (b < 2048) { src = x; dst = xb; off = b; }
  else {
    const int t = b - 2048;
    const int z = t >> 9;
    if (z < 3) { src = (z==0) ? wq : ((z==1) ? wk : wv); dst = wb + (size_t)z*EMB*EMB; }
    else       { src = wo; dst = wob; }
    off = t & 511;
  }
  const int i = (off*256 + threadIdx.x)*8;
  const float4* s4 = (const float4*)(src + i);
  *(ushort8*)(dst + i) = cvt8(s4[0], s4[1]);
}

// ---------------- QKV projection, A+B bf16, dbuf, swizzled (r15) ----------
__global__ __launch_bounds__(256) void k_qkv_bb(
    const unsigned short* __restrict__ xb,
    const unsigned short* __restrict__ wb,
    const float* __restrict__ bq, const float* __restrict__ bk,
    const float* __restrict__ bv,
    unsigned short* __restrict__ Qb, unsigned short* __restrict__ Kb,
    unsigned short* __restrict__ Vtb)
{
  __shared__ unsigned short Al[2][128*32];
  __shared__ unsigned short Bl[2][128*32];
  const int tid = threadIdx.x;
  const int lin  = blockIdx.x;
  const int wgid = (lin & 7)*96 + (lin >> 3);
  const int mb   = wgid / 24;
  const int t    = wgid % 24;
  const int z    = t >> 3;
  const int nb   = t & 7;
  const int m0 = mb * 128;
  const int n0 = nb * 128;
  const int w = tid >> 6, lane = tid & 63;
  const int wr = w >> 1, wc = w & 1;
  const int lr = lane & 15, lhi = lane >> 4;
  const unsigned short* wz = wb + (size_t)z * (EMB*EMB);

  // staging: thread c fills physical 16B slot c; source = inverse swizzle
  const unsigned short* ag[2];
  const unsigned short* bg[2];
  int ub[2];
#pragma unroll
  for (int j=0;j<2;++j) {
    const int c    = j*256 + tid;
    const int line = c >> 3;
    const int sp   = (c & 7) ^ (line & 7);
    const int row  = line*2 + (sp >> 2);
    const int q    = sp & 3;
    ag[j] = xb + (size_t)(m0+row)*EMB + q*8;
    bg[j] = wz + (size_t)(n0+row)*EMB + q*8;
    ub[j] = (j*256 + (tid & 192)) * 16;
  }

  auto STAGE = [&](int k0, int b2) {
#pragma unroll
    for (int j=0;j<2;++j) {
      GLOAD16(ag[j] + k0, (char*)Al[b2] + ub[j]);
      GLOAD16(bg[j] + k0, (char*)Bl[b2] + ub[j]);
    }
  };

  // frag-read bases (t-invariant): slot = ((lr&1)*4+lhi) ^ (lr>>1)
  const int asl  = (((lr & 1) << 2) + lhi) ^ (lr >> 1);
  const int rb   = (lr >> 1)*128 + asl*16;
  const int abase = wr*4096 + rb;
  const int bbase = wc*4096 + rb;

  f32x4 acc[4][4];
#pragma unroll
  for (int m=0;m<4;++m)
#pragma unroll
    for (int n=0;n<4;++n) acc[m][n] = (f32x4){0.f,0.f,0.f,0.f};

  STAGE(0, 0);
  int bbuf = 0;
  for (int k0 = 0; k0 < EMB; k0 += 32) {
    if (k0 + 32 < EMB) {
      STAGE(k0 + 32, bbuf^1);
      asm volatile("s_waitcnt vmcnt(4)" ::: "memory");
    } else {
      asm volatile("s_waitcnt vmcnt(0)" ::: "memory");
    }
    __builtin_amdgcn_s_barrier();

    bf16x8 af[4], bfr[4];
#pragma unroll
    for (int m=0;m<4;++m) af[m]  = *(const bf16x8*)((char*)Al[bbuf] + abase + m*1024);
#pragma unroll
    for (int n=0;n<4;++n) bfr[n] = *(const bf16x8*)((char*)Bl[bbuf] + bbase + n*1024);
    __builtin_amdgcn_s_setprio(1);
#pragma unroll
    for (int m=0;m<4;++m)
#pragma unroll
      for (int n=0;n<4;++n)
        acc[m][n] = __builtin_amdgcn_mfma_f32_16x16x32_bf16(af[m], bfr[n], acc[m][n], 0,0,0);
    __builtin_amdgcn_s_setprio(0);

    __builtin_amdgcn_s_barrier();
    bbuf ^= 1;
  }

  const float scale = (z==0) ? 0.125f*LOG2E : 1.0f;
  const float* bias = (z==0) ? bq : ((z==1) ? bk : bv);
#pragma unroll
  for (int m=0;m<4;++m)
#pragma unroll
    for (int n=0;n<4;++n)
#pragma unroll
      for (int r=0;r<4;++r) {
        const int rr   = m0 + wr*64 + m*16 + lhi*4 + r;
        const int fcol = n0 + wc*64 + n*16 + lr;
        const float v = (acc[m][n][r] + bias[fcol]) * scale;
        const unsigned short ov = f2bf(v);
        const int i = rr >> 1, bsel = rr & 1;
        const int h = fcol >> 6, d = fcol & 63;
        const int hh = bsel*NH + h;
        if (z == 0)      Qb [((size_t)hh*S_LEN + i)*HD + d] = ov;
        else if (z == 1) Kb [((size_t)hh*S_LEN + i)*HD + d] = ov;
        else             Vtb[((size_t)hh*HD + d)*S_LEN + i] = ov;
      }
}

// ---------------- QKV projection, bf16 A / fp32 B (32MB tier) ------------
__global__ __launch_bounds__(256) void k_qkv_bf(
    const unsigned short* __restrict__ xb,
    const float* __restrict__ wq, const float* __restrict__ wk,
    const float* __restrict__ wv,
    const float* __restrict__ bq, const float* __restrict__ bk,
    const float* __restrict__ bv,
    unsigned short* __restrict__ Qb, unsigned short* __restrict__ Kb,
    unsigned short* __restrict__ Vtb)
{
  __shared__ unsigned short Al[128*32];
  __shared__ unsigned short Bl[128*32];
  const int tid = threadIdx.x;
  const int lin  = blockIdx.x;
  const int wgid = (lin & 7)*96 + (lin >> 3);
  const int mb   = wgid / 24;
  const int t    = wgid % 24;
  const int z    = t >> 3;
  const int nb   = t & 7;
  const int m0 = mb * 128;
  const int n0 = nb * 128;
  const int w = tid >> 6, lane = tid & 63;
  const int wr = w >> 1, wc = w & 1;
  const int lr = lane & 15, lhi = lane >> 4;
  const float* wz = (z==0) ? wq : ((z==1) ? wk : wv);

  f32x4 acc[4][4];
#pragma unroll
  for (int m=0;m<4;++m)
#pragma unroll
    for (int n=0;n<4;++n) acc[m][n] = (f32x4){0.f,0.f,0.f,0.f};

  for (int k0 = 0; k0 < EMB; k0 += 32) {
    float4 b0[2], b1[2];
#pragma unroll
    for (int j = 0; j < 2; ++j) {
      const int c   = j*256 + tid;
      const int row = c >> 2;
      const int col = (c & 3) << 3;
      const float* bp = wz + (size_t)(n0+row)*EMB + k0 + col;
      b0[j] = *(const float4*)bp;  b1[j] = *(const float4*)(bp+4);
    }
    __syncthreads();
#pragma unroll
    for (int j = 0; j < 2; ++j) {
      const int c   = j*256 + tid;
      const int row = c >> 2;
      const int col = (c & 3) << 3;
      const int ub  = (j*256 + (tid & 192)) * 16;
      GLOAD16(xb + (size_t)(m0+row)*EMB + k0 + col, (char*)Al + ub);
      *(ushort8*)&Bl[row*32 + col] = cvt8(b0[j], b1[j]);
    }
    __syncthreads();
    bf16x8 af[4], bfr[4];
#pragma unroll
    for (int m=0;m<4;++m) af[m]  = *(const bf16x8*)&Al[(wr*64 + m*16 + lr)*32 + lhi*8];
#pragma unroll
    for (int n=0;n<4;++n) bfr[n] = *(const bf16x8*)&Bl[(wc*64 + n*16 + lr)*32 + lhi*8];
#pragma unroll
    for (int m=0;m<4;++m)
#pragma unroll
      for (int n=0;n<4;++n)
        acc[m][n] = __builtin_amdgcn_mfma_f32_16x16x32_bf16(af[m], bfr[n], acc[m][n], 0,0,0);
  }

  const float scale = (z==0) ? 0.125f*LOG2E : 1.0f;
  const float* bias = (z==0) ? bq : ((z==1) ? bk : bv);
#pragma unroll
  for (int m=0;m<4;++m)
#pragma unroll
    for (int n=0;n<4;++n)
#pragma unroll
      for (int r=0;r<4;++r) {
        const int rr   = m0 + wr*64 + m*16 + lhi*4 + r;
        const int fcol = n0 + wc*64 + n*16 + lr;
        const float v = (acc[m][n][r] + bias[fcol]) * scale;
        const unsigned short ov = f2bf(v);
        const int i = rr >> 1, bsel = rr & 1;
        const int h = fcol >> 6, d = fcol & 63;
        const int hh = bsel*NH + h;
        if (z == 0)      Qb [((size_t)hh*S_LEN + i)*HD + d] = ov;
        else if (z == 1) Kb [((size_t)hh*S_LEN + i)*HD + d] = ov;
        else             Vtb[((size_t)hh*HD + d)*S_LEN + i] = ov;
      }
}

// ---------------- QKV projection, fp32 A (small-ws fallback) ------------
__global__ __launch_bounds__(256) void k_qkv(
    const float* __restrict__ xA, int a_rs, int ishift,
    const float* __restrict__ wq, const float* __restrict__ wk,
    const float* __restrict__ wv,
    const float* __restrict__ bq, const float* __restrict__ bk,
    const float* __restrict__ bv,
    unsigned short* __restrict__ Qb, unsigned short* __restrict__ Kb,
    unsigned short* __restrict__ Vtb)
{
  __shared__ unsigned short Al[128*32];
  __shared__ unsigned short Bl[128*32];
  const int tid = threadIdx.x;
  const int z  = blockIdx.z;
  const int m0 = blockIdx.x * 128;
  const int n0 = blockIdx.y * 128;
  const int w = tid >> 6, lane = tid & 63;
  const int wr = w >> 1, wc = w & 1;
  const int lr = lane & 15, lhi = lane >> 4;
  const float* wz = (z==0) ? wq : ((z==1) ? wk : wv);

  f32x4 acc[4][4];
#pragma unroll
  for (int m=0;m<4;++m)
#pragma unroll
    for (int n=0;n<4;++n) acc[m][n] = (f32x4){0.f,0.f,0.f,0.f};

  for (int k0 = 0; k0 < EMB; k0 += 32) {
    float4 a0[2], a1[2], b0[2], b1[2];
#pragma unroll
    for (int j = 0; j < 2; ++j) {
      const int c   = j*256 + tid;
      const int row = c >> 2;
      const int col = (c & 3) << 3;
      const float* ap = xA + (size_t)(m0+row)*a_rs + k0 + col;
      const float* bp = wz + (size_t)(n0+row)*EMB + k0 + col;
      a0[j] = *(const float4*)ap;  a1[j] = *(const float4*)(ap+4);
      b0[j] = *(const float4*)bp;  b1[j] = *(const float4*)(bp+4);
    }
    __syncthreads();
#pragma unroll
    for (int j = 0; j < 2; ++j) {
      const int c   = j*256 + tid;
      const int row = c >> 2;
      const int col = (c & 3) << 3;
      *(ushort8*)&Al[row*32 + col] = cvt8(a0[j], a1[j]);
      *(ushort8*)&Bl[row*32 + col] = cvt8(b0[j], b1[j]);
    }
    __syncthreads();
    bf16x8 af[4], bfr[4];
#pragma unroll
    for (int m=0;m<4;++m) af[m]  = *(const bf16x8*)&Al[(wr*64 + m*16 + lr)*32 + lhi*8];
#pragma unroll
    for (int n=0;n<4;++n) bfr[n] = *(const bf16x8*)&Bl[(wc*64 + n*16 + lr)*32 + lhi*8];
#pragma unroll
    for (int m=0;m<4;++m)
#pragma unroll
      for (int n=0;n<4;++n)
        acc[m][n] = __builtin_amdgcn_mfma_f32_16x16x32_bf16(af[m], bfr[n], acc[m][n], 0,0,0);
  }

  const float scale = (z==0) ? 0.125f*LOG2E : 1.0f;
  const float* bias = (z==0) ? bq : ((z==1) ? bk : bv);
  const int bmask = (1 << ishift) - 1;
#pragma unroll
  for (int m=0;m<4;++m)
#pragma unroll
    for (int n=0;n<4;++n)
#pragma unroll
      for (int r=0;r<4;++r) {
        const int rr   = m0 + wr*64 + m*16 + lhi*4 + r;
        const int fcol = n0 + wc*64 + n*16 + lr;
        const float v = (acc[m][n][r] + bias[fcol]) * scale;
        const unsigned short ov = f2bf(v);
        const int i = rr >> ishift, bsel = rr & bmask;
        const int h = fcol >> 6, d = fcol & 63;
        const int hh = bsel*NH + h;
        if (z == 0)      Qb [((size_t)hh*S_LEN + i)*HD + d] = ov;
        else if (z == 1) Kb [((size_t)hh*S_LEN + i)*HD + d] = ov;
        else             Vtb[((size_t)hh*HD + d)*S_LEN + i] = ov;
      }
}

// ---------------- causal flash attention (r14: K+V LDS-staged, no-max) ----
// REVERTED from r15's V-from-global (16-segment scatters + vmcnt pollution
// serialized the pipeline). K/V 64-tiles double-buffered via global_load_lds,
// counted vmcnt(4); no-max exp2 softmax; lane-partial rl; uint2 P-pack.
__global__ __launch_bounds__(256,4) void k_attn_u(
    const unsigned short* __restrict__ Q,
    const unsigned short* __restrict__ K,
    const unsigned short* __restrict__ Vt,
    unsigned short* __restrict__ ctx, int bshift, int hsh)
{
  __shared__ unsigned short KL[2][64*64];
  __shared__ unsigned short VL[2][64*64];
  __shared__ unsigned short Pl[4][16*64];

  const int tid = threadIdx.x;
  const int w = tid >> 6, lane = tid & 63;
  const int lr = lane & 15, lhi = lane >> 4;

  const int lin = blockIdx.x;
  const int cc  = lin >> hsh;
  const int chunk = (cc < 16) ? cc : (47 - cc);
  const int hh  = lin & ((1 << hsh) - 1);
  const int q0  = chunk*64 + w*16;

  const unsigned short* Qh = Q  + (size_t)hh*S_LEN*HD;
  const unsigned short* Kh = K  + (size_t)hh*S_LEN*HD;
  const unsigned short* Vh = Vt + (size_t)hh*HD*S_LEN;
  char* Pw = (char*)Pl[w];

  const int xm = (lr & 7) << 4;
  int kvb[2];
#pragma unroll
  for (int kf=0;kf<2;++kf) kvb[kf] = lr*128 + ((kf*64 + lhi*16) ^ xm);
  int pwb[4];
#pragma unroll
  for (int kn=0;kn<4;++kn)
    pwb[kn] = lr*128 + ((kn*32 + lhi*8) ^ xm);

  const unsigned short* kga[2];
  const unsigned short* vga[2];
#pragma unroll
  for (int j=0;j<2;++j) {
    const int c   = j*256 + tid;
    const int row = c >> 3;
    const int sb  = (c*16) ^ ((row & 7) << 4);
    const int el  = (sb & 127) >> 1;
    kga[j] = Kh + (size_t)row*HD + el;
    vga[j] = Vh + (size_t)row*S_LEN + el;
  }
  const int ub0 = (tid & 192) * 16;

  bf16x8 qf[2];
#pragma unroll
  for (int kf=0;kf<2;++kf)
    qf[kf] = *(const bf16x8*)&Qh[(size_t)(q0 + lr)*HD + kf*32 + lhi*8];

  f32x4 o[4];
  float rl = 0.f;                 // lane-partial; reduced in epilogue
#pragma unroll
  for (int dn=0;dn<4;++dn) o[dn] = (f32x4){0.f,0.f,0.f,0.f};

  const int tmax = chunk + 1;

  auto STAGE = [&](int tt, int bb2) {
#pragma unroll
    for (int j=0;j<2;++j) {
      GLOAD16(kga[j] + (size_t)tt*4096, (char*)KL[bb2] + ub0 + j*4096);
      GLOAD16(vga[j] + (size_t)tt*64,   (char*)VL[bb2] + ub0 + j*4096);
    }
  };

  STAGE(0, 0);
  int bb = 0;
  for (int t = 0; t < tmax; ++t) {
    if (t + 1 < tmax) {
      STAGE(t+1, bb^1);
      asm volatile("s_waitcnt vmcnt(4)" ::: "memory");
    } else {
      asm volatile("s_waitcnt vmcnt(0)" ::: "memory");
    }
    __builtin_amdgcn_s_barrier();

    const int kv0 = t*64;
    const char* KB = (const char*)KL[bb];
    const char* VB = (const char*)VL[bb];

    f32x4 st[4];
#pragma unroll
    for (int kn=0;kn<4;++kn) st[kn] = (f32x4){0.f,0.f,0.f,0.f};

    __builtin_amdgcn_s_setprio(1);
#pragma unroll
    for (int kn=0;kn<4;++kn)
#pragma unroll
      for (int kf=0;kf<2;++kf) {
        const bf16x8 kfr = *(const bf16x8*)(KB + kvb[kf] + kn*2048);
        st[kn] = __builtin_amdgcn_mfma_f32_16x16x32_bf16(kfr, qf[kf], st[kn], 0,0,0);
      }
    __builtin_amdgcn_s_setprio(0);

    if (t == tmax-1) {   // diagonal tile: mask k > q (exp2f(-1e30) == 0)
      const int q = q0 + lr;
#pragma unroll
      for (int kn=0;kn<4;++kn)
#pragma unroll
        for (int r=0;r<4;++r) {
          const int k = kv0 + kn*16 + lhi*4 + r;
          if (k > q) st[kn][r] = -1.0e30f;
        }
    }

    // no-max softmax: p = exp2f(s) directly
#pragma unroll
    for (int kn=0;kn<4;++kn)
#pragma unroll
      for (int r=0;r<4;++r) {
        const float p = exp2f(st[kn][r]);
        st[kn][r] = p;
        rl += p;
      }

#pragma unroll
    for (int kn=0;kn<4;++kn)
      *(uint2*)(Pw + pwb[kn]) = pack4(st[kn]);

    // PV: O^T += MFMA(A = V^T rows, B = P rows)
#pragma unroll
    for (int ks=0;ks<2;++ks) {
      const bf16x8 pfr = *(const bf16x8*)(Pw + kvb[ks]);
      __builtin_amdgcn_s_setprio(1);
#pragma unroll
      for (int dn=0;dn<4;++dn) {
        const bf16x8 vf = *(const bf16x8*)(VB + kvb[ks] + dn*2048);
        o[dn] = __builtin_amdgcn_mfma_f32_16x16x32_bf16(vf, pfr, o[dn], 0,0,0);
      }
      __builtin_amdgcn_s_setprio(0);
    }

    __builtin_amdgcn_s_barrier();
    bb ^= 1;
  }

  rl += __shfl_xor(rl, 16);
  rl += __shfl_xor(rl, 32);
  const int h = hh & (NH-1);
  const int badd = hh >> 4;
  const float inv = 1.0f / rl;
  const int q = q0 + lr;
  const size_t trow = ((size_t)q << bshift) + badd;
#pragma unroll
  for (int dn=0;dn<4;++dn) {
    f32x4 ov;
#pragma unroll
    for (int r=0;r<4;++r) ov[r] = o[dn][r]*inv;
    *(uint2*)&ctx[trow*EMB + h*HD + dn*16 + lhi*4] = pack4(ov);
  }
}

// ---------------- output projection, bf16 A+B, dbuf, swizzled (r15) -------
__global__ __launch_bounds__(256) void k_oproj_bf(
    const unsigned short* __restrict__ ctxA,
    const unsigned short* __restrict__ wob,
    const float* __restrict__ bo,
    float* __restrict__ out)
{
  __shared__ unsigned short Al[2][128*32];
  __shared__ unsigned short Bl[2][128*32];
  const int tid = threadIdx.x;
  const int m0 = blockIdx.x * 128;
  const int n0 = blockIdx.y * 128;
  const int w = tid >> 6, lane = tid & 63;
  const int wr = w >> 1, wc = w & 1;
  const int lr = lane & 15, lhi = lane >> 4;

  const unsigned short* ag[2];
  const unsigned short* bg[2];
  int ub[2];
#pragma unroll
  for (int j=0;j<2;++j) {
    const int c    = j*256 + tid;
    const int line = c >> 3;
    const int sp   = (c & 7) ^ (line & 7);
    const int row  = line*2 + (sp >> 2);
    const int q    = sp & 3;
    ag[j] = ctxA + (size_t)(m0+row)*EMB + q*8;
    bg[j] = wob  + (size_t)(n0+row)*EMB + q*8;
    ub[j] = (j*256 + (tid & 192)) * 16;
  }

  auto STAGE = [&](int k0, int b2) {
#pragma unroll
    for (int j=0;j<2;++j) {
      GLOAD16(ag[j] + k0, (char*)Al[b2] + ub[j]);
      GLOAD16(bg[j] + k0, (char*)Bl[b2] + ub[j]);
    }
  };

  const int asl  = (((lr & 1) << 2) + lhi) ^ (lr >> 1);
  const int rb   = (lr >> 1)*128 + asl*16;
  const int abase = wr*4096 + rb;
  const int bbase = wc*4096 + rb;

  f32x4 acc[4][4];
#pragma unroll
  for (int m=0;m<4;++m)
#pragma unroll
    for (int n=0;n<4;++n) acc[m][n] = (f32x4){0.f,0.f,0.f,0.f};

  STAGE(0, 0);
  int bbuf = 0;
  for (int k0 = 0; k0 < EMB; k0 += 32) {
    if (k0 + 32 < EMB) {
      STAGE(k0 + 32, bbuf^1);
      asm volatile("s_waitcnt vmcnt(4)" ::: "memory");
    } else {
      asm volatile("s_waitcnt vmcnt(0)" ::: "memory");
    }
    __builtin_amdgcn_s_barrier();

    bf16x8 af[4], bfr[4];
#pragma unroll
    for (int m=0;m<4;++m) af[m]  = *(const bf16x8*)((char*)Al[bbuf] + abase + m*1024);
#pragma unroll
    for (int n=0;n<4;++n) bfr[n] = *(const bf16x8*)((char*)Bl[bbuf] + bbase + n*1024);
    __builtin_amdgcn_s_setprio(1);
#pragma unroll
    for (int m=0;m<4;++m)
#pragma unroll
      for (int n=0;n<4;++n)
        acc[m][n] = __builtin_amdgcn_mfma_f32_16x16x32_bf16(af[m], bfr[n], acc[m][n], 0,0,0);
    __builtin_amdgcn_s_setprio(0);

    __builtin_amdgcn_s_barrier();
    bbuf ^= 1;
  }

#pragma unroll
  for (int m=0;m<4;++m)
#pragma unroll
    for (int n=0;n<4;++n)
#pragma unroll
      for (int r=0;r<4;++r) {
        const int rr   = m0 + wr*64 + m*16 + lhi*4 + r;
        const int fcol = n0 + wc*64 + n*16 + lr;
        out[(size_t)rr*EMB + fcol] = acc[m][n][r] + bo[fcol];
      }
}

// ---------------- output projection, fp32 B (fallback) -------------------
__global__ __launch_bounds__(256) void k_oproj(
    const unsigned short* __restrict__ ctxA,
    const float* __restrict__ wo,
    const float* __restrict__ bo,
    float* __restrict__ outb, int orm)
{
  __shared__ unsigned short Al[128*32];
  __shared__ unsigned short Bl[128*32];
  const int tid = threadIdx.x;
  const int m0 = blockIdx.x * 128;
  const int n0 = blockIdx.y * 128;
  const int w = tid >> 6, lane = tid & 63;
  const int wr = w >> 1, wc = w & 1;
  const int lr = lane & 15, lhi = lane >> 4;

  f32x4 acc[4][4];
#pragma unroll
  for (int m=0;m<4;++m)
#pragma unroll
    for (int n=0;n<4;++n) acc[m][n] = (f32x4){0.f,0.f,0.f,0.f};

  for (int k0 = 0; k0 < EMB; k0 += 32) {
    float4 b0[2], b1[2];
#pragma unroll
    for (int j = 0; j < 2; ++j) {
      const int c   = j*256 + tid;
      const int row = c >> 2;
      const int col = (c & 3) << 3;
      const float* bp = wo + (size_t)(n0+row)*EMB + k0 + col;
      b0[j] = *(const float4*)bp;  b1[j] = *(const float4*)(bp+4);
    }
    __syncthreads();
#pragma unroll
    for (int j = 0; j < 2; ++j) {
      const int c   = j*256 + tid;
      const int row = c >> 2;
      const int col = (c & 3) << 3;
      const int ub  = (j*256 + (tid & 192)) * 16;
      GLOAD16(ctxA + (size_t)(m0+row)*EMB + k0 + col, (char*)Al + ub);
      *(ushort8*)&Bl[row*32 + col] = cvt8(b0[j], b1[j]);
    }
    __syncthreads();
    bf16x8 af[4], bfr[4];
#pragma unroll
    for (int m=0;m<4;++m) af[m]  = *(const bf16x8*)&Al[(wr*64 + m*16 + lr)*32 + lhi*8];
#pragma unroll
    for (int n=0;n<4;++n) bfr[n] = *(const bf16x8*)&Bl[(wc*64 + n*16 + lr)*32 + lhi*8];
#pragma unroll
    for (int m=0;m<4;++m)
#pragma unroll
      for (int n=0;n<4;++n)
        acc[m][n] = __builtin_amdgcn_mfma_f32_16x16x32_bf16(af[m], bfr[n], acc[m][n], 0,0,0);
  }

#pragma unroll
  for (int m=0;m<4;++m)
#pragma unroll
    for (int n=0;n<4;++n)
#pragma unroll
      for (int r=0;r<4;++r) {
        const int rr   = m0 + wr*64 + m*16 + lhi*4 + r;
        const int fcol = n0 + wc*64 + n*16 + lr;
        outb[(size_t)rr*orm*EMB + fcol] = acc[m][n][r] + bo[fcol];
      }
}

// ---------------- launch ----------------
extern "C" void kernel_launch(void* const* d_in, const int* in_sizes, int n_in,
                              void* d_out, int out_size, void* d_ws, size_t ws_size,
                              hipStream_t stream) {
  const float* x  = (const float*)d_in[0];
  const float* wq = (const float*)d_in[1];
  const float* bq = (const float*)d_in[2];
  const float* wk = (const float*)d_in[3];
  const float* bk = (const float*)d_in[4];
  const float* wv = (const float*)d_in[5];
  const float* bv = (const float*)d_in[6];
  const float* wo = (const float*)d_in[7];
  const float* bo = (const float*)d_in[8];
  float* out = (float*)d_out;

  char* ws = (char*)d_ws;
  const size_t MB = (size_t)1 << 20;

  if (ws_size >= 40*MB) {
    unsigned short* Q   = (unsigned short*)(ws + 0*MB);
    unsigned short* K   = (unsigned short*)(ws + 8*MB);
    unsigned short* Vt  = (unsigned short*)(ws + 16*MB);
    unsigned short* wb  = (unsigned short*)(ws + 24*MB);
    unsigned short* xb  = (unsigned short*)(ws + 30*MB);
    unsigned short* wob = (unsigned short*)(ws + 38*MB);
    unsigned short* cx  = (unsigned short*)(ws + 24*MB);

    k_cvt_all<<<4096, 256, 0, stream>>>(x, wq, wk, wv, wo, xb, wb, wob);
    k_qkv_bb<<<768, 256, 0, stream>>>(xb, wb, bq,bk,bv, Q, K, Vt);
    k_attn_u<<<1024, 256, 0, stream>>>(Q, K, Vt, cx, 1, 5);
    k_oproj_bf<<<dim3(32,8), 256, 0, stream>>>(cx, wob, bo, out);
  } else if (ws_size >= 38*MB) {
    unsigned short* Q   = (unsigned short*)(ws + 0*MB);
    unsigned short* K   = (unsigned short*)(ws + 8*MB);
    unsigned short* Vt  = (unsigned short*)(ws + 16*MB);
    unsigned short* wb  = (unsigned short*)(ws + 24*MB);
    unsigned short* xb  = (unsigned short*)(ws + 30*MB);
    unsigned short* cx  = (unsigned short*)(ws + 24*MB);
    unsigned short* wob = Vt;

    k_cvt_all<<<3584, 256, 0, stream>>>(x, wq, wk, wv, wo, xb, wb, (unsigned short*)0);
    k_qkv_bb<<<768, 256, 0, stream>>>(xb, wb, bq,bk,bv, Q, K, Vt);
    k_attn_u<<<1024, 256, 0, stream>>>(Q, K, Vt, cx, 1, 5);
    k_cvt<<<512, 256, 0, stream>>>(wo, wob, EMB*EMB);
    k_oproj_bf<<<dim3(32,8), 256, 0, stream>>>(cx, wob, bo, out);
  } else if (ws_size >= 32*MB) {
    unsigned short* Q   = (unsigned short*)(ws + 0*MB);
    unsigned short* K   = (unsigned short*)(ws + 8*MB);
    unsigned short* Vt  = (unsigned short*)(ws + 16*MB);
    unsigned short* cx  = (unsigned short*)(ws + 24*MB);
    unsigned short* xb  = cx;
    unsigned short* wob = Vt;

    k_cvt<<<2048, 256, 0, stream>>>(x, xb, (S_LEN*BATCH)*EMB);
    k_qkv_bf<<<768, 256, 0, stream>>>(xb, wq,wk,wv, bq,bk,bv, Q, K, Vt);
    k_attn_u<<<1024, 256, 0, stream>>>(Q, K, Vt, cx, 1, 5);
    k_cvt<<<512, 256, 0, stream>>>(wo, wob, EMB*EMB);
    k_oproj_bf<<<dim3(32,8), 256, 0, stream>>>(cx, wob, bo, out);
  } else {
    unsigned short* Q  = (unsigned short*)(ws + 0*MB);
    unsigned short* K  = (unsigned short*)(ws + 4*MB);
    unsigned short* Vt = (unsigned short*)(ws + 8*MB);
    unsigned short* cx = (unsigned short*)(ws + 12*MB);
    for (int b = 0; b < 2; ++b) {
      k_qkv<<<dim3(16,8,3), 256, 0, stream>>>(x + b*EMB, 2*EMB, 0,
                                              wq,wk,wv, bq,bk,bv, Q,K,Vt);
      k_attn_u<<<512, 256, 0, stream>>>(Q, K, Vt, cx, 0, 4);
      k_oproj<<<dim3(16,8), 256, 0, stream>>>(cx, wo, bo, out + b*EMB, 2);
    }
  }
}

// Round 18
// 110.194 us; speedup vs baseline: 1.3037x; 1.0141x over previous
//
#include <hip/hip_runtime.h>
#include <hip/hip_bf16.h>
#include <stdint.h>

#define S_LEN 2048
#define BATCH 2
#define EMB   1024
#define NH    16
#define HD    64
#define LOG2E 1.4426950408889634f

typedef __bf16 bf16x8 __attribute__((ext_vector_type(8)));
typedef float  f32x4  __attribute__((ext_vector_type(4)));
typedef unsigned short ushort8 __attribute__((ext_vector_type(8)));

__device__ __forceinline__ unsigned short f2bf(float f) {
  __bf16 h = (__bf16)f;
  return __builtin_bit_cast(unsigned short, h);
}

__device__ __forceinline__ ushort8 cvt8(const float4 a, const float4 b) {
  ushort8 o;
  o[0]=f2bf(a.x); o[1]=f2bf(a.y); o[2]=f2bf(a.z); o[3]=f2bf(a.w);
  o[4]=f2bf(b.x); o[5]=f2bf(b.y); o[6]=f2bf(b.z); o[7]=f2bf(b.w);
  return o;
}

__device__ __forceinline__ uint2 pack4(const f32x4 v) {
  uint2 r;
  r.x = (unsigned)f2bf(v[0]) | ((unsigned)f2bf(v[1]) << 16);
  r.y = (unsigned)f2bf(v[2]) | ((unsigned)f2bf(v[3]) << 16);
  return r;
}

#define GLOAD16(g, l) __builtin_amdgcn_global_load_lds( \
    (const __attribute__((address_space(1))) void*)(g),  \
    (__attribute__((address_space(3))) void*)(l), 16, 0, 0)

// ---------------- fp32 -> bf16 conversion (single src) ----------------
__global__ __launch_bounds__(256) void k_cvt(const float* __restrict__ src,
                                             unsigned short* __restrict__ dst,
                                             int n) {
  int i = (blockIdx.x*256 + threadIdx.x)*8;
  if (i >= n) return;
  const float4* s4 = (const float4*)(src + i);
  *(ushort8*)(dst + i) = cvt8(s4[0], s4[1]);
}

// ------- fused cvt: x (2048 blk) + wq/wk/wv (512 each) [+ wo (512)] ------
__global__ __launch_bounds__(256) void k_cvt_all(
    const float* __restrict__ x,
    const float* __restrict__ wq, const float* __restrict__ wk,
    const float* __restrict__ wv, const float* __restrict__ wo,
    unsigned short* __restrict__ xb, unsigned short* __restrict__ wb,
    unsigned short* __restrict__ wob) {
  const int b = blockIdx.x;
  const float* src;
  unsigned short* dst;
  int off;
  if (b < 2048) { src = x; dst = xb; off = b; }
  else {
    const int t = b - 2048;
    const int z = t >> 9;
    if (z < 3) { src = (z==0) ? wq : ((z==1) ? wk : wv); dst = wb + (size_t)z*EMB*EMB; }
    else       { src = wo; dst = wob; }
    off = t & 511;
  }
  const int i = (off*256 + threadIdx.x)*8;
  const float4* s4 = (const float4*)(src + i);
  *(ushort8*)(dst + i) = cvt8(s4[0], s4[1]);
}

// ---------------- QKV projection, A+B bf16, dbuf, swizzled ----------------
// V (z==2) epilogue goes through an LDS transpose so V^T global stores are
// b128 with 8 lanes per d-row (8 segments x 128B per instr) instead of
// 64-way 2B scatters. SB is the staging buffer reused for the transpose.
__global__ __launch_bounds__(256) void k_qkv_bb(
    const unsigned short* __restrict__ xb,
    const unsigned short* __restrict__ wb,
    const float* __restrict__ bq, const float* __restrict__ bk,
    const float* __restrict__ bv,
    unsigned short* __restrict__ Qb, unsigned short* __restrict__ Kb,
    unsigned short* __restrict__ Vtb)
{
  __shared__ unsigned short SB[16896];     // 33.8 KB: staging (32KB) / transpose

  const int tid = threadIdx.x;
  const int lin  = blockIdx.x;
  const int wgid = (lin & 7)*96 + (lin >> 3);
  const int mb   = wgid / 24;
  const int t    = wgid % 24;
  const int z    = t >> 3;
  const int nb   = t & 7;
  const int m0 = mb * 128;
  const int n0 = nb * 128;
  const int w = tid >> 6, lane = tid & 63;
  const int wr = w >> 1, wc = w & 1;
  const int lr = lane & 15, lhi = lane >> 4;
  const unsigned short* wz = wb + (size_t)z * (EMB*EMB);

  // staging: thread c fills physical 16B slot c; source = inverse swizzle
  const unsigned short* ag[2];
  const unsigned short* bg[2];
  int ub[2];
#pragma unroll
  for (int j=0;j<2;++j) {
    const int c    = j*256 + tid;
    const int line = c >> 3;
    const int sp   = (c & 7) ^ (line & 7);
    const int row  = line*2 + (sp >> 2);
    const int q    = sp & 3;
    ag[j] = xb + (size_t)(m0+row)*EMB + q*8;
    bg[j] = wz + (size_t)(n0+row)*EMB + q*8;
    ub[j] = (j*256 + (tid & 192)) * 16;
  }

  auto STAGE = [&](int k0, int b2) {
#pragma unroll
    for (int j=0;j<2;++j) {
      GLOAD16(ag[j] + k0, (char*)(SB + b2*4096)        + ub[j]);   // A buf
      GLOAD16(bg[j] + k0, (char*)(SB + 8192 + b2*4096) + ub[j]);   // B buf
    }
  };

  // frag-read bases (t-invariant): slot = ((lr&1)*4+lhi) ^ (lr>>1)
  const int asl  = (((lr & 1) << 2) + lhi) ^ (lr >> 1);
  const int rb   = (lr >> 1)*128 + asl*16;
  const int abase = wr*4096 + rb;
  const int bbase = wc*4096 + rb;

  f32x4 acc[4][4];
#pragma unroll
  for (int m=0;m<4;++m)
#pragma unroll
    for (int n=0;n<4;++n) acc[m][n] = (f32x4){0.f,0.f,0.f,0.f};

  STAGE(0, 0);
  int bbuf = 0;
  for (int k0 = 0; k0 < EMB; k0 += 32) {
    if (k0 + 32 < EMB) {
      STAGE(k0 + 32, bbuf^1);
      asm volatile("s_waitcnt vmcnt(4)" ::: "memory");
    } else {
      asm volatile("s_waitcnt vmcnt(0)" ::: "memory");
    }
    __builtin_amdgcn_s_barrier();

    const char* Ab = (const char*)(SB + bbuf*4096);
    const char* Bb = (const char*)(SB + 8192 + bbuf*4096);
    bf16x8 af[4], bfr[4];
#pragma unroll
    for (int m=0;m<4;++m) af[m]  = *(const bf16x8*)(Ab + abase + m*1024);
#pragma unroll
    for (int n=0;n<4;++n) bfr[n] = *(const bf16x8*)(Bb + bbase + n*1024);
    __builtin_amdgcn_s_setprio(1);
#pragma unroll
    for (int m=0;m<4;++m)
#pragma unroll
      for (int n=0;n<4;++n)
        acc[m][n] = __builtin_amdgcn_mfma_f32_16x16x32_bf16(af[m], bfr[n], acc[m][n], 0,0,0);
    __builtin_amdgcn_s_setprio(0);

    __builtin_amdgcn_s_barrier();
    bbuf ^= 1;
  }

  if (z == 2) {
    // ---- V epilogue: LDS transpose -> coalesced b128 stores ----
    // layout: T[bsel][fcol_local(128)][i_local(64)+2pad], row stride 66
    unsigned short* T = SB;   // safe: loop ended with s_barrier (reads drained)
#pragma unroll
    for (int m=0;m<4;++m)
#pragma unroll
      for (int n=0;n<4;++n) {
        const int fl = wc*64 + n*16 + lr;
        const int i0 = wr*32 + m*8 + lhi*2;           // even
        const float b = bv[n0 + fl];
        const unsigned w0 = (unsigned)f2bf(acc[m][n][0] + b)
                          | ((unsigned)f2bf(acc[m][n][2] + b) << 16);  // bsel 0
        const unsigned w1 = (unsigned)f2bf(acc[m][n][1] + b)
                          | ((unsigned)f2bf(acc[m][n][3] + b) << 16);  // bsel 1
        *(unsigned*)&T[fl*66 + i0]        = w0;
        *(unsigned*)&T[8448 + fl*66 + i0] = w1;
      }
    __builtin_amdgcn_s_barrier();
    const int h = n0 >> 6;   // n0 covers 2 h values: h + (fl>>6)
#pragma unroll
    for (int it = 0; it < 8; ++it) {
      const int jj   = it*256 + tid;          // 0..2047
      const int bsel = jj >> 10;
      const int fl   = (jj >> 3) & 127;
      const int ic   = (jj & 7) * 8;
      const ushort8 vv = *(const ushort8*)&T[bsel*8448 + fl*66 + ic];
      const int hh2 = bsel*NH + h + (fl >> 6);
      const int d   = fl & 63;
      *(ushort8*)&Vtb[((size_t)hh2*HD + d)*S_LEN + (m0 >> 1) + ic] = vv;
    }
  } else {
    const float scale = (z==0) ? 0.125f*LOG2E : 1.0f;
    const float* bias = (z==0) ? bq : bk;
    unsigned short* qk = (z==0) ? Qb : Kb;
#pragma unroll
    for (int m=0;m<4;++m)
#pragma unroll
      for (int n=0;n<4;++n)
#pragma unroll
        for (int r=0;r<4;++r) {
          const int rr   = m0 + wr*64 + m*16 + lhi*4 + r;
          const int fcol = n0 + wc*64 + n*16 + lr;
          const float v = (acc[m][n][r] + bias[fcol]) * scale;
          const unsigned short ov = f2bf(v);
          const int i = rr >> 1, bsel = rr & 1;
          const int h = fcol >> 6, d = fcol & 63;
          const int hh = bsel*NH + h;
          qk[((size_t)hh*S_LEN + i)*HD + d] = ov;
        }
  }
}

// ---------------- QKV projection, bf16 A / fp32 B (32MB tier) ------------
__global__ __launch_bounds__(256) void k_qkv_bf(
    const unsigned short* __restrict__ xb,
    const float* __restrict__ wq, const float* __restrict__ wk,
    const float* __restrict__ wv,
    const float* __restrict__ bq, const float* __restrict__ bk,
    const float* __restrict__ bv,
    unsigned short* __restrict__ Qb, unsigned short* __restrict__ Kb,
    unsigned short* __restrict__ Vtb)
{
  __shared__ unsigned short Al[128*32];
  __shared__ unsigned short Bl[128*32];
  const int tid = threadIdx.x;
  const int lin  = blockIdx.x;
  const int wgid = (lin & 7)*96 + (lin >> 3);
  const int mb   = wgid / 24;
  const int t    = wgid % 24;
  const int z    = t >> 3;
  const int nb   = t & 7;
  const int m0 = mb * 128;
  const int n0 = nb * 128;
  const int w = tid >> 6, lane = tid & 63;
  const int wr = w >> 1, wc = w & 1;
  const int lr = lane & 15, lhi = lane >> 4;
  const float* wz = (z==0) ? wq : ((z==1) ? wk : wv);

  f32x4 acc[4][4];
#pragma unroll
  for (int m=0;m<4;++m)
#pragma unroll
    for (int n=0;n<4;++n) acc[m][n] = (f32x4){0.f,0.f,0.f,0.f};

  for (int k0 = 0; k0 < EMB; k0 += 32) {
    float4 b0[2], b1[2];
#pragma unroll
    for (int j = 0; j < 2; ++j) {
      const int c   = j*256 + tid;
      const int row = c >> 2;
      const int col = (c & 3) << 3;
      const float* bp = wz + (size_t)(n0+row)*EMB + k0 + col;
      b0[j] = *(const float4*)bp;  b1[j] = *(const float4*)(bp+4);
    }
    __syncthreads();
#pragma unroll
    for (int j = 0; j < 2; ++j) {
      const int c   = j*256 + tid;
      const int row = c >> 2;
      const int col = (c & 3) << 3;
      const int ub  = (j*256 + (tid & 192)) * 16;
      GLOAD16(xb + (size_t)(m0+row)*EMB + k0 + col, (char*)Al + ub);
      *(ushort8*)&Bl[row*32 + col] = cvt8(b0[j], b1[j]);
    }
    __syncthreads();
    bf16x8 af[4], bfr[4];
#pragma unroll
    for (int m=0;m<4;++m) af[m]  = *(const bf16x8*)&Al[(wr*64 + m*16 + lr)*32 + lhi*8];
#pragma unroll
    for (int n=0;n<4;++n) bfr[n] = *(const bf16x8*)&Bl[(wc*64 + n*16 + lr)*32 + lhi*8];
#pragma unroll
    for (int m=0;m<4;++m)
#pragma unroll
      for (int n=0;n<4;++n)
        acc[m][n] = __builtin_amdgcn_mfma_f32_16x16x32_bf16(af[m], bfr[n], acc[m][n], 0,0,0);
  }

  const float scale = (z==0) ? 0.125f*LOG2E : 1.0f;
  const float* bias = (z==0) ? bq : ((z==1) ? bk : bv);
#pragma unroll
  for (int m=0;m<4;++m)
#pragma unroll
    for (int n=0;n<4;++n)
#pragma unroll
      for (int r=0;r<4;++r) {
        const int rr   = m0 + wr*64 + m*16 + lhi*4 + r;
        const int fcol = n0 + wc*64 + n*16 + lr;
        const float v = (acc[m][n][r] + bias[fcol]) * scale;
        const unsigned short ov = f2bf(v);
        const int i = rr >> 1, bsel = rr & 1;
        const int h = fcol >> 6, d = fcol & 63;
        const int hh = bsel*NH + h;
        if (z == 0)      Qb [((size_t)hh*S_LEN + i)*HD + d] = ov;
        else if (z == 1) Kb [((size_t)hh*S_LEN + i)*HD + d] = ov;
        else             Vtb[((size_t)hh*HD + d)*S_LEN + i] = ov;
      }
}

// ---------------- QKV projection, fp32 A (small-ws fallback) ------------
__global__ __launch_bounds__(256) void k_qkv(
    const float* __restrict__ xA, int a_rs, int ishift,
    const float* __restrict__ wq, const float* __restrict__ wk,
    const float* __restrict__ wv,
    const float* __restrict__ bq, const float* __restrict__ bk,
    const float* __restrict__ bv,
    unsigned short* __restrict__ Qb, unsigned short* __restrict__ Kb,
    unsigned short* __restrict__ Vtb)
{
  __shared__ unsigned short Al[128*32];
  __shared__ unsigned short Bl[128*32];
  const int tid = threadIdx.x;
  const int z  = blockIdx.z;
  const int m0 = blockIdx.x * 128;
  const int n0 = blockIdx.y * 128;
  const int w = tid >> 6, lane = tid & 63;
  const int wr = w >> 1, wc = w & 1;
  const int lr = lane & 15, lhi = lane >> 4;
  const float* wz = (z==0) ? wq : ((z==1) ? wk : wv);

  f32x4 acc[4][4];
#pragma unroll
  for (int m=0;m<4;++m)
#pragma unroll
    for (int n=0;n<4;++n) acc[m][n] = (f32x4){0.f,0.f,0.f,0.f};

  for (int k0 = 0; k0 < EMB; k0 += 32) {
    float4 a0[2], a1[2], b0[2], b1[2];
#pragma unroll
    for (int j = 0; j < 2; ++j) {
      const int c   = j*256 + tid;
      const int row = c >> 2;
      const int col = (c & 3) << 3;
      const float* ap = xA + (size_t)(m0+row)*a_rs + k0 + col;
      const float* bp = wz + (size_t)(n0+row)*EMB + k0 + col;
      a0[j] = *(const float4*)ap;  a1[j] = *(const float4*)(ap+4);
      b0[j] = *(const float4*)bp;  b1[j] = *(const float4*)(bp+4);
    }
    __syncthreads();
#pragma unroll
    for (int j = 0; j < 2; ++j) {
      const int c   = j*256 + tid;
      const int row = c >> 2;
      const int col = (c & 3) << 3;
      *(ushort8*)&Al[row*32 + col] = cvt8(a0[j], a1[j]);
      *(ushort8*)&Bl[row*32 + col] = cvt8(b0[j], b1[j]);
    }
    __syncthreads();
    bf16x8 af[4], bfr[4];
#pragma unroll
    for (int m=0;m<4;++m) af[m]  = *(const bf16x8*)&Al[(wr*64 + m*16 + lr)*32 + lhi*8];
#pragma unroll
    for (int n=0;n<4;++n) bfr[n] = *(const bf16x8*)&Bl[(wc*64 + n*16 + lr)*32 + lhi*8];
#pragma unroll
    for (int m=0;m<4;++m)
#pragma unroll
      for (int n=0;n<4;++n)
        acc[m][n] = __builtin_amdgcn_mfma_f32_16x16x32_bf16(af[m], bfr[n], acc[m][n], 0,0,0);
  }

  const float scale = (z==0) ? 0.125f*LOG2E : 1.0f;
  const float* bias = (z==0) ? bq : ((z==1) ? bk : bv);
  const int bmask = (1 << ishift) - 1;
#pragma unroll
  for (int m=0;m<4;++m)
#pragma unroll
    for (int n=0;n<4;++n)
#pragma unroll
      for (int r=0;r<4;++r) {
        const int rr   = m0 + wr*64 + m*16 + lhi*4 + r;
        const int fcol = n0 + wc*64 + n*16 + lr;
        const float v = (acc[m][n][r] + bias[fcol]) * scale;
        const unsigned short ov = f2bf(v);
        const int i = rr >> ishift, bsel = rr & bmask;
        const int h = fcol >> 6, d = fcol & 63;
        const int hh = bsel*NH + h;
        if (z == 0)      Qb [((size_t)hh*S_LEN + i)*HD + d] = ov;
        else if (z == 1) Kb [((size_t)hh*S_LEN + i)*HD + d] = ov;
        else             Vtb[((size_t)hh*HD + d)*S_LEN + i] = ov;
      }
}

// ---------------- causal flash attention (r14/r16 structure, frozen) ------
__global__ __launch_bounds__(256,4) void k_attn_u(
    const unsigned short* __restrict__ Q,
    const unsigned short* __restrict__ K,
    const unsigned short* __restrict__ Vt,
    unsigned short* __restrict__ ctx, int bshift, int hsh)
{
  __shared__ unsigned short KL[2][64*64];
  __shared__ unsigned short VL[2][64*64];
  __shared__ unsigned short Pl[4][16*64];

  const int tid = threadIdx.x;
  const int w = tid >> 6, lane = tid & 63;
  const int lr = lane & 15, lhi = lane >> 4;

  const int lin = blockIdx.x;
  const int cc  = lin >> hsh;
  const int chunk = (cc < 16) ? cc : (47 - cc);
  const int hh  = lin & ((1 << hsh) - 1);
  const int q0  = chunk*64 + w*16;

  const unsigned short* Qh = Q  + (size_t)hh*S_LEN*HD;
  const unsigned short* Kh = K  + (size_t)hh*S_LEN*HD;
  const unsigned short* Vh = Vt + (size_t)hh*HD*S_LEN;
  char* Pw = (char*)Pl[w];

  const int xm = (lr & 7) << 4;
  int kvb[2];
#pragma unroll
  for (int kf=0;kf<2;++kf) kvb[kf] = lr*128 + ((kf*64 + lhi*16) ^ xm);
  int pwb[4];
#pragma unroll
  for (int kn=0;kn<4;++kn)
    pwb[kn] = lr*128 + ((kn*32 + lhi*8) ^ xm);

  const unsigned short* kga[2];
  const unsigned short* vga[2];
#pragma unroll
  for (int j=0;j<2;++j) {
    const int c   = j*256 + tid;
    const int row = c >> 3;
    const int sb  = (c*16) ^ ((row & 7) << 4);
    const int el  = (sb & 127) >> 1;
    kga[j] = Kh + (size_t)row*HD + el;
    vga[j] = Vh + (size_t)row*S_LEN + el;
  }
  const int ub0 = (tid & 192) * 16;

  bf16x8 qf[2];
#pragma unroll
  for (int kf=0;kf<2;++kf)
    qf[kf] = *(const bf16x8*)&Qh[(size_t)(q0 + lr)*HD + kf*32 + lhi*8];

  f32x4 o[4];
  float rl = 0.f;
#pragma unroll
  for (int dn=0;dn<4;++dn) o[dn] = (f32x4){0.f,0.f,0.f,0.f};

  const int tmax = chunk + 1;

  auto STAGE = [&](int tt, int bb2) {
#pragma unroll
    for (int j=0;j<2;++j) {
      GLOAD16(kga[j] + (size_t)tt*4096, (char*)KL[bb2] + ub0 + j*4096);
      GLOAD16(vga[j] + (size_t)tt*64,   (char*)VL[bb2] + ub0 + j*4096);
    }
  };

  STAGE(0, 0);
  int bb = 0;
  for (int t = 0; t < tmax; ++t) {
    if (t + 1 < tmax) {
      STAGE(t+1, bb^1);
      asm volatile("s_waitcnt vmcnt(4)" ::: "memory");
    } else {
      asm volatile("s_waitcnt vmcnt(0)" ::: "memory");
    }
    __builtin_amdgcn_s_barrier();

    const int kv0 = t*64;
    const char* KB = (const char*)KL[bb];
    const char* VB = (const char*)VL[bb];

    f32x4 st[4];
#pragma unroll
    for (int kn=0;kn<4;++kn) st[kn] = (f32x4){0.f,0.f,0.f,0.f};

    __builtin_amdgcn_s_setprio(1);
#pragma unroll
    for (int kn=0;kn<4;++kn)
#pragma unroll
      for (int kf=0;kf<2;++kf) {
        const bf16x8 kfr = *(const bf16x8*)(KB + kvb[kf] + kn*2048);
        st[kn] = __builtin_amdgcn_mfma_f32_16x16x32_bf16(kfr, qf[kf], st[kn], 0,0,0);
      }
    __builtin_amdgcn_s_setprio(0);

    if (t == tmax-1) {
      const int q = q0 + lr;
#pragma unroll
      for (int kn=0;kn<4;++kn)
#pragma unroll
        for (int r=0;r<4;++r) {
          const int k = kv0 + kn*16 + lhi*4 + r;
          if (k > q) st[kn][r] = -1.0e30f;
        }
    }

#pragma unroll
    for (int kn=0;kn<4;++kn)
#pragma unroll
      for (int r=0;r<4;++r) {
        const float p = exp2f(st[kn][r]);
        st[kn][r] = p;
        rl += p;
      }

#pragma unroll
    for (int kn=0;kn<4;++kn)
      *(uint2*)(Pw + pwb[kn]) = pack4(st[kn]);

#pragma unroll
    for (int ks=0;ks<2;++ks) {
      const bf16x8 pfr = *(const bf16x8*)(Pw + kvb[ks]);
      __builtin_amdgcn_s_setprio(1);
#pragma unroll
      for (int dn=0;dn<4;++dn) {
        const bf16x8 vf = *(const bf16x8*)(VB + kvb[ks] + dn*2048);
        o[dn] = __builtin_amdgcn_mfma_f32_16x16x32_bf16(vf, pfr, o[dn], 0,0,0);
      }
      __builtin_amdgcn_s_setprio(0);
    }

    __builtin_amdgcn_s_barrier();
    bb ^= 1;
  }

  rl += __shfl_xor(rl, 16);
  rl += __shfl_xor(rl, 32);
  const int h = hh & (NH-1);
  const int badd = hh >> 4;
  const float inv = 1.0f / rl;
  const int q = q0 + lr;
  const size_t trow = ((size_t)q << bshift) + badd;
#pragma unroll
  for (int dn=0;dn<4;++dn) {
    f32x4 ov;
#pragma unroll
    for (int r=0;r<4;++r) ov[r] = o[dn][r]*inv;
    *(uint2*)&ctx[trow*EMB + h*HD + dn*16 + lhi*4] = pack4(ov);
  }
}

// ---------------- output projection, bf16 A+B, dbuf, swizzled -------------
__global__ __launch_bounds__(256) void k_oproj_bf(
    const unsigned short* __restrict__ ctxA,
    const unsigned short* __restrict__ wob,
    const float* __restrict__ bo,
    float* __restrict__ out)
{
  __shared__ unsigned short Al[2][128*32];
  __shared__ unsigned short Bl[2][128*32];
  const int tid = threadIdx.x;
  const int m0 = blockIdx.x * 128;
  const int n0 = blockIdx.y * 128;
  const int w = tid >> 6, lane = tid & 63;
  const int wr = w >> 1, wc = w & 1;
  const int lr = lane & 15, lhi = lane >> 4;

  const unsigned short* ag[2];
  const unsigned short* bg[2];
  int ub[2];
#pragma unroll
  for (int j=0;j<2;++j) {
    const int c    = j*256 + tid;
    const int line = c >> 3;
    const int sp   = (c & 7) ^ (line & 7);
    const int row  = line*2 + (sp >> 2);
    const int q    = sp & 3;
    ag[j] = ctxA + (size_t)(m0+row)*EMB + q*8;
    bg[j] = wob  + (size_t)(n0+row)*EMB + q*8;
    ub[j] = (j*256 + (tid & 192)) * 16;
  }

  auto STAGE = [&](int k0, int b2) {
#pragma unroll
    for (int j=0;j<2;++j) {
      GLOAD16(ag[j] + k0, (char*)Al[b2] + ub[j]);
      GLOAD16(bg[j] + k0, (char*)Bl[b2] + ub[j]);
    }
  };

  const int asl  = (((lr & 1) << 2) + lhi) ^ (lr >> 1);
  const int rb   = (lr >> 1)*128 + asl*16;
  const int abase = wr*4096 + rb;
  const int bbase = wc*4096 + rb;

  f32x4 acc[4][4];
#pragma unroll
  for (int m=0;m<4;++m)
#pragma unroll
    for (int n=0;n<4;++n) acc[m][n] = (f32x4){0.f,0.f,0.f,0.f};

  STAGE(0, 0);
  int bbuf = 0;
  for (int k0 = 0; k0 < EMB; k0 += 32) {
    if (k0 + 32 < EMB) {
      STAGE(k0 + 32, bbuf^1);
      asm volatile("s_waitcnt vmcnt(4)" ::: "memory");
    } else {
      asm volatile("s_waitcnt vmcnt(0)" ::: "memory");
    }
    __builtin_amdgcn_s_barrier();

    bf16x8 af[4], bfr[4];
#pragma unroll
    for (int m=0;m<4;++m) af[m]  = *(const bf16x8*)((char*)Al[bbuf] + abase + m*1024);
#pragma unroll
    for (int n=0;n<4;++n) bfr[n] = *(const bf16x8*)((char*)Bl[bbuf] + bbase + n*1024);
    __builtin_amdgcn_s_setprio(1);
#pragma unroll
    for (int m=0;m<4;++m)
#pragma unroll
      for (int n=0;n<4;++n)
        acc[m][n] = __builtin_amdgcn_mfma_f32_16x16x32_bf16(af[m], bfr[n], acc[m][n], 0,0,0);
    __builtin_amdgcn_s_setprio(0);

    __builtin_amdgcn_s_barrier();
    bbuf ^= 1;
  }

#pragma unroll
  for (int m=0;m<4;++m)
#pragma unroll
    for (int n=0;n<4;++n)
#pragma unroll
      for (int r=0;r<4;++r) {
        const int rr   = m0 + wr*64 + m*16 + lhi*4 + r;
        const int fcol = n0 + wc*64 + n*16 + lr;
        out[(size_t)rr*EMB + fcol] = acc[m][n][r] + bo[fcol];
      }
}

// ---------------- output projection, fp32 B (fallback) -------------------
__global__ __launch_bounds__(256) void k_oproj(
    const unsigned short* __restrict__ ctxA,
    const float* __restrict__ wo,
    const float* __restrict__ bo,
    float* __restrict__ outb, int orm)
{
  __shared__ unsigned short Al[128*32];
  __shared__ unsigned short Bl[128*32];
  const int tid = threadIdx.x;
  const int m0 = blockIdx.x * 128;
  const int n0 = blockIdx.y * 128;
  const int w = tid >> 6, lane = tid & 63;
  const int wr = w >> 1, wc = w & 1;
  const int lr = lane & 15, lhi = lane >> 4;

  f32x4 acc[4][4];
#pragma unroll
  for (int m=0;m<4;++m)
#pragma unroll
    for (int n=0;n<4;++n) acc[m][n] = (f32x4){0.f,0.f,0.f,0.f};

  for (int k0 = 0; k0 < EMB; k0 += 32) {
    float4 b0[2], b1[2];
#pragma unroll
    for (int j = 0; j < 2; ++j) {
      const int c   = j*256 + tid;
      const int row = c >> 2;
      const int col = (c & 3) << 3;
      const float* bp = wo + (size_t)(n0+row)*EMB + k0 + col;
      b0[j] = *(const float4*)bp;  b1[j] = *(const float4*)(bp+4);
    }
    __syncthreads();
#pragma unroll
    for (int j = 0; j < 2; ++j) {
      const int c   = j*256 + tid;
      const int row = c >> 2;
      const int col = (c & 3) << 3;
      const int ub  = (j*256 + (tid & 192)) * 16;
      GLOAD16(ctxA + (size_t)(m0+row)*EMB + k0 + col, (char*)Al + ub);
      *(ushort8*)&Bl[row*32 + col] = cvt8(b0[j], b1[j]);
    }
    __syncthreads();
    bf16x8 af[4], bfr[4];
#pragma unroll
    for (int m=0;m<4;++m) af[m]  = *(const bf16x8*)&Al[(wr*64 + m*16 + lr)*32 + lhi*8];
#pragma unroll
    for (int n=0;n<4;++n) bfr[n] = *(const bf16x8*)&Bl[(wc*64 + n*16 + lr)*32 + lhi*8];
#pragma unroll
    for (int m=0;m<4;++m)
#pragma unroll
      for (int n=0;n<4;++n)
        acc[m][n] = __builtin_amdgcn_mfma_f32_16x16x32_bf16(af[m], bfr[n], acc[m][n], 0,0,0);
  }

#pragma unroll
  for (int m=0;m<4;++m)
#pragma unroll
    for (int n=0;n<4;++n)
#pragma unroll
      for (int r=0;r<4;++r) {
        const int rr   = m0 + wr*64 + m*16 + lhi*4 + r;
        const int fcol = n0 + wc*64 + n*16 + lr;
        outb[(size_t)rr*orm*EMB + fcol] = acc[m][n][r] + bo[fcol];
      }
}

// ---------------- launch ----------------
extern "C" void kernel_launch(void* const* d_in, const int* in_sizes, int n_in,
                              void* d_out, int out_size, void* d_ws, size_t ws_size,
                              hipStream_t stream) {
  const float* x  = (const float*)d_in[0];
  const float* wq = (const float*)d_in[1];
  const float* bq = (const float*)d_in[2];
  const float* wk = (const float*)d_in[3];
  const float* bk = (const float*)d_in[4];
  const float* wv = (const float*)d_in[5];
  const float* bv = (const float*)d_in[6];
  const float* wo = (const float*)d_in[7];
  const float* bo = (const float*)d_in[8];
  float* out = (float*)d_out;

  char* ws = (char*)d_ws;
  const size_t MB = (size_t)1 << 20;

  if (ws_size >= 40*MB) {
    unsigned short* Q   = (unsigned short*)(ws + 0*MB);
    unsigned short* K   = (unsigned short*)(ws + 8*MB);
    unsigned short* Vt  = (unsigned short*)(ws + 16*MB);
    unsigned short* wb  = (unsigned short*)(ws + 24*MB);
    unsigned short* xb  = (unsigned short*)(ws + 30*MB);
    unsigned short* wob = (unsigned short*)(ws + 38*MB);
    unsigned short* cx  = (unsigned short*)(ws + 24*MB);

    k_cvt_all<<<4096, 256, 0, stream>>>(x, wq, wk, wv, wo, xb, wb, wob);
    k_qkv_bb<<<768, 256, 0, stream>>>(xb, wb, bq,bk,bv, Q, K, Vt);
    k_attn_u<<<1024, 256, 0, stream>>>(Q, K, Vt, cx, 1, 5);
    k_oproj_bf<<<dim3(32,8), 256, 0, stream>>>(cx, wob, bo, out);
  } else if (ws_size >= 38*MB) {
    unsigned short* Q   = (unsigned short*)(ws + 0*MB);
    unsigned short* K   = (unsigned short*)(ws + 8*MB);
    unsigned short* Vt  = (unsigned short*)(ws + 16*MB);
    unsigned short* wb  = (unsigned short*)(ws + 24*MB);
    unsigned short* xb  = (unsigned short*)(ws + 30*MB);
    unsigned short* cx  = (unsigned short*)(ws + 24*MB);
    unsigned short* wob = Vt;

    k_cvt_all<<<3584, 256, 0, stream>>>(x, wq, wk, wv, wo, xb, wb, (unsigned short*)0);
    k_qkv_bb<<<768, 256, 0, stream>>>(xb, wb, bq,bk,bv, Q, K, Vt);
    k_attn_u<<<1024, 256, 0, stream>>>(Q, K, Vt, cx, 1, 5);
    k_cvt<<<512, 256, 0, stream>>>(wo, wob, EMB*EMB);
    k_oproj_bf<<<dim3(32,8), 256, 0, stream>>>(cx, wob, bo, out);
  } else if (ws_size >= 32*MB) {
    unsigned short* Q   = (unsigned short*)(ws + 0*MB);
    unsigned short* K   = (unsigned short*)(ws + 8*MB);
    unsigned short* Vt  = (unsigned short*)(ws + 16*MB);
    unsigned short* cx  = (unsigned short*)(ws + 24*MB);
    unsigned short* xb  = cx;
    unsigned short* wob = Vt;

    k_cvt<<<2048, 256, 0, stream>>>(x, xb, (S_LEN*BATCH)*EMB);
    k_qkv_bf<<<768, 256, 0, stream>>>(xb, wq,wk,wv, bq,bk,bv, Q, K, Vt);
    k_attn_u<<<1024, 256, 0, stream>>>(Q, K, Vt, cx, 1, 5);
    k_cvt<<<512, 256, 0, stream>>>(wo, wob, EMB*EMB);
    k_oproj_bf<<<dim3(32,8), 256, 0, stream>>>(cx, wob, bo, out);
  } else {
    unsigned short* Q  = (unsigned short*)(ws + 0*MB);
    unsigned short* K  = (unsigned short*)(ws + 4*MB);
    unsigned short* Vt = (unsigned short*)(ws + 8*MB);
    unsigned short* cx = (unsigned short*)(ws + 12*MB);
    for (int b = 0; b < 2; ++b) {
      k_qkv<<<dim3(16,8,3), 256, 0, stream>>>(x + b*EMB, 2*EMB, 0,
                                              wq,wk,wv, bq,bk,bv, Q,K,Vt);
      k_attn_u<<<512, 256, 0, stream>>>(Q, K, Vt, cx, 0, 4);
      k_oproj<<<dim3(16,8), 256, 0, stream>>>(cx, wo, bo, out + b*EMB, 2);
    }
  }
}